// Round 1
// baseline (1094.033 us; speedup 1.0000x reference)
//
#include <hip/hip_runtime.h>
#include <cstdint>

#define NN 20000
#define NE 640000
#define NEG_SLOPE 0.1f

// ---------------- weight packing ----------------
__global__ __launch_bounds__(256) void pack_weights(
    const float* __restrict__ Wpe, const float* __restrict__ Wgos, const float* __restrict__ Wprot,
    const float* __restrict__ bpe, const float* __restrict__ bgos, const float* __restrict__ bprot,
    const float* __restrict__ Wom0, const float* __restrict__ Wom1,
    const float* __restrict__ Wom2, const float* __restrict__ Wom3,
    const float* __restrict__ bom0, const float* __restrict__ bom1,
    const float* __restrict__ bom2, const float* __restrict__ bom3,
    float* __restrict__ Wcat, float* __restrict__ bcat,
    float* __restrict__ Womc, float* __restrict__ bomc)
{
    int idx = blockIdx.x * blockDim.x + threadIdx.x;
    const int T1 = 736 * 384, T2 = 54 * 384;
    if (idx < T1) {
        int row = idx / 384, col = idx % 384;
        float v;
        if (row < 128)      v = Wpe[row * 384 + col];
        else if (row < 256) v = Wgos[(row - 128) * 384 + col];
        else                v = Wprot[(row - 256) * 384 + col];
        Wcat[idx] = v;
    } else if (idx < T1 + T2) {
        int j = idx - T1;
        int row = j / 384, col = j % 384;
        float v;
        if (row < 3)       v = Wom0[row * 384 + col];
        else if (row < 6)  v = Wom1[(row - 3) * 384 + col];
        else if (row < 30) v = Wom2[(row - 6) * 384 + col];
        else               v = Wom3[(row - 30) * 384 + col];
        Womc[j] = v;
    } else if (idx < T1 + T2 + 384) {
        int c = idx - T1 - T2;
        bcat[c] = bpe[c] + bgos[c] + bprot[c];
        bomc[c] = bom0[c] + bom1[c] + bom2[c] + bom3[c];
    }
}

// ---------------- degree / CSR ----------------
__global__ __launch_bounds__(256) void count_deg(const int* __restrict__ dst, int* __restrict__ cnt)
{
    int e = blockIdx.x * blockDim.x + threadIdx.x;
    if (e < NE) atomicAdd(&cnt[dst[e]], 1);
}

__global__ __launch_bounds__(256) void make_deginv(const int* __restrict__ cnt, float* __restrict__ deg_inv)
{
    int i = blockIdx.x * blockDim.x + threadIdx.x;
    if (i < NN) deg_inv[i] = rsqrtf((float)cnt[i] + 2.0f);
}

// single-block exclusive scan of cnt[0..NN) -> ofs[0..NN], also copies to cursor
__global__ __launch_bounds__(256) void scan_kernel(const int* __restrict__ cnt,
                                                   int* __restrict__ ofs, int* __restrict__ cursor)
{
    __shared__ int part[256];
    const int t = threadIdx.x;
    const int CH = (NN + 255) / 256;
    int base = t * CH;
    int s = 0;
    for (int i = 0; i < CH; i++) { int idx = base + i; if (idx < NN) s += cnt[idx]; }
    part[t] = s;
    __syncthreads();
    for (int off = 1; off < 256; off <<= 1) {
        int v = (t >= off) ? part[t - off] : 0;
        __syncthreads();
        part[t] += v;
        __syncthreads();
    }
    int run = (t == 0) ? 0 : part[t - 1];
    for (int i = 0; i < CH; i++) {
        int idx = base + i;
        if (idx < NN) { ofs[idx] = run; cursor[idx] = run; run += cnt[idx]; }
    }
    if (t == 255) ofs[NN] = run;
}

__global__ __launch_bounds__(256) void fill_csr(const int* __restrict__ src, const int* __restrict__ dst,
                                                const float* __restrict__ deg_inv,
                                                int* __restrict__ cursor,
                                                int* __restrict__ csr_src, float* __restrict__ csr_cf)
{
    int e = blockIdx.x * blockDim.x + threadIdx.x;
    if (e >= NE) return;
    int s = src[e], d = dst[e];
    int p = atomicAdd(&cursor[d], 1);
    csr_src[p] = s;
    csr_cf[p] = deg_inv[s] * deg_inv[d];
}

// ---------------- SGEMM: C = [act](A(nrows x K, lda) @ W(K x M) [+ bias]) ----------------
template<int BM, int BN, bool BIASACT>
__global__ __launch_bounds__(256) void sgemm_kernel(
    const float* __restrict__ A, int lda,
    const float* __restrict__ W,
    const float* __restrict__ bias,
    float* __restrict__ C,
    int nrows, int K, int M)
{
    constexpr int BK = 16;
    constexpr int TM = BM / 16;
    constexpr int TN = BN / 16;
    __shared__ float As[BK][BM];
    __shared__ float Ws[BK][BN];

    const int t = threadIdx.x;
    const int row0 = blockIdx.y * BM;
    const int col0 = blockIdx.x * BN;
    const int tr = t >> 4;
    const int tc = t & 15;

    float acc[TM][TN];
#pragma unroll
    for (int i = 0; i < TM; i++)
#pragma unroll
        for (int j = 0; j < TN; j++) acc[i][j] = 0.f;

    const bool vec4 = ((K & 3) == 0) && ((lda & 3) == 0);
    const int a_r = t >> 2;
    const int a_k = (t & 3) * 4;
    constexpr int W_TPR = BN / 4;
    const int w_r = t / W_TPR;
    const int w_n = (t % W_TPR) * 4;
    constexpr int W_RPP = 256 / W_TPR;
    constexpr int W_PASS = BK / W_RPP;
    constexpr int A_PASS = BM / 64;

    for (int k0 = 0; k0 < K; k0 += BK) {
#pragma unroll
        for (int p = 0; p < A_PASS; p++) {
            int r = a_r + p * 64;
            int grow = row0 + r;
            float4 v = make_float4(0.f, 0.f, 0.f, 0.f);
            if (grow < nrows) {
                if (vec4 && (k0 + a_k + 4 <= K)) {
                    v = *reinterpret_cast<const float4*>(&A[(size_t)grow * lda + k0 + a_k]);
                } else {
                    float tmp[4];
#pragma unroll
                    for (int q = 0; q < 4; q++) {
                        int kk = k0 + a_k + q;
                        tmp[q] = (kk < K) ? A[(size_t)grow * lda + kk] : 0.f;
                    }
                    v = make_float4(tmp[0], tmp[1], tmp[2], tmp[3]);
                }
            }
            As[a_k + 0][r] = v.x; As[a_k + 1][r] = v.y;
            As[a_k + 2][r] = v.z; As[a_k + 3][r] = v.w;
        }
#pragma unroll
        for (int p = 0; p < W_PASS; p++) {
            int r = w_r + p * W_RPP;
            int gk = k0 + r;
            float4 v = make_float4(0.f, 0.f, 0.f, 0.f);
            if (gk < K) v = *reinterpret_cast<const float4*>(&W[(size_t)gk * M + col0 + w_n]);
            *reinterpret_cast<float4*>(&Ws[r][w_n]) = v;
        }
        __syncthreads();
#pragma unroll
        for (int k = 0; k < BK; k++) {
            float a[TM], b[TN];
#pragma unroll
            for (int i = 0; i < 4; i++) a[i] = As[k][tr * 4 + i];
            if constexpr (TM == 8) {
#pragma unroll
                for (int i = 0; i < 4; i++) a[4 + i] = As[k][64 + tr * 4 + i];
            }
#pragma unroll
            for (int j = 0; j < 4; j++) b[j] = Ws[k][tc * 4 + j];
            if constexpr (TN == 8) {
#pragma unroll
                for (int j = 0; j < 4; j++) b[4 + j] = Ws[k][64 + tc * 4 + j];
            }
#pragma unroll
            for (int i = 0; i < TM; i++)
#pragma unroll
                for (int j = 0; j < TN; j++)
                    acc[i][j] = fmaf(a[i], b[j], acc[i][j]);
        }
        __syncthreads();
    }

#pragma unroll
    for (int i = 0; i < TM; i++) {
        int r = (TM == 8) ? ((i < 4) ? tr * 4 + i : 64 + tr * 4 + (i - 4)) : tr * 4 + i;
        int grow = row0 + r;
        if (grow >= nrows) continue;
#pragma unroll
        for (int jg = 0; jg < TN / 4; jg++) {
            int cb = (TN == 8) ? ((jg == 0) ? tc * 4 : 64 + tc * 4) : tc * 4;
            int gcol = col0 + cb;
            float4 v;
            float* vp = &v.x;
#pragma unroll
            for (int q = 0; q < 4; q++) {
                float xv = acc[i][jg * 4 + q];
                if constexpr (BIASACT) {
                    xv += bias[gcol + q];
                    xv = (xv > 0.f) ? xv : NEG_SLOPE * xv;
                }
                vp[q] = xv;
            }
            *reinterpret_cast<float4*>(&C[(size_t)grow * M + gcol]) = v;
        }
    }
}

static void launch_gemm(hipStream_t st, const float* A, int lda, const float* W,
                        const float* bias, float* C, int nrows, int K, int M, bool biasact)
{
    if (M % 128 == 0 && M >= 256) {
        dim3 g(M / 128, (nrows + 127) / 128), b(256);
        if (biasact) sgemm_kernel<128, 128, true><<<g, b, 0, st>>>(A, lda, W, bias, C, nrows, K, M);
        else         sgemm_kernel<128, 128, false><<<g, b, 0, st>>>(A, lda, W, bias, C, nrows, K, M);
    } else {
        dim3 g(M / 64, (nrows + 63) / 64), b(256);
        if (biasact) sgemm_kernel<64, 64, true><<<g, b, 0, st>>>(A, lda, W, bias, C, nrows, K, M);
        else         sgemm_kernel<64, 64, false><<<g, b, 0, st>>>(A, lda, W, bias, C, nrows, K, M);
    }
}

// ---------------- fused GCN aggregation for both chains ----------------
// block = node i; threads 0..127 -> h chain feature t, 128..255 -> g chain feature t-128
__global__ __launch_bounds__(256) void aggregate2(
    const float* __restrict__ hWc, const float* __restrict__ hWo,
    const float* __restrict__ bc, const float* __restrict__ bo,
    const int* __restrict__ ofs, const int* __restrict__ csr_src,
    const float* __restrict__ csr_cf, const float* __restrict__ deg_inv,
    float* __restrict__ outbase, int hcol, int gcol)
{
    __shared__ int s_src[128];
    __shared__ float s_cf[128];
    const int i = blockIdx.x;
    const int t = threadIdx.x;
    const int f = t & 127;
    const bool isH = (t < 128);
    const float* __restrict__ hW = isH ? hWc : hWo;
    const int start = ofs[i], end = ofs[i + 1];
    const float di = deg_inv[i];
    float acc = hW[(size_t)i * 128 + f] * (2.0f * di * di);
    for (int base = start; base < end; base += 128) {
        int n = end - base; if (n > 128) n = 128;
        __syncthreads();
        if (t < n) { s_src[t] = csr_src[base + t]; s_cf[t] = csr_cf[base + t]; }
        __syncthreads();
        int e = 0;
        for (; e + 4 <= n; e += 4) {
            int s0 = s_src[e], s1 = s_src[e + 1], s2 = s_src[e + 2], s3 = s_src[e + 3];
            float c0 = s_cf[e], c1 = s_cf[e + 1], c2 = s_cf[e + 2], c3 = s_cf[e + 3];
            float v0 = hW[(size_t)s0 * 128 + f];
            float v1 = hW[(size_t)s1 * 128 + f];
            float v2 = hW[(size_t)s2 * 128 + f];
            float v3 = hW[(size_t)s3 * 128 + f];
            acc = fmaf(v0, c0, acc); acc = fmaf(v1, c1, acc);
            acc = fmaf(v2, c2, acc); acc = fmaf(v3, c3, acc);
        }
        for (; e < n; e++) acc = fmaf(hW[(size_t)s_src[e] * 128 + f], s_cf[e], acc);
    }
    float b = isH ? bc[f] : bo[f];
    float v = acc + b;
    v = (v > 0.f) ? v : NEG_SLOPE * v;
    int col = isH ? hcol : gcol;
    outbase[(size_t)i * 768 + col + f] = v;
}

// ---------------- final 2-wide heads ----------------
__global__ __launch_bounds__(256) void heads_kernel(
    const float* __restrict__ td, const float* __restrict__ ts,
    const float* __restrict__ Wod, const float* __restrict__ bod,
    const float* __restrict__ Wos, const float* __restrict__ bos,
    float* __restrict__ out)
{
    int i = blockIdx.x * blockDim.x + threadIdx.x;
    if (i >= NN) return;
    float a0 = bod[0], a1 = bod[1], d0 = bos[0], d1 = bos[1];
    for (int k = 0; k < 128; k++) {
        float vd = td[(size_t)i * 128 + k];
        float vs = ts[(size_t)i * 128 + k];
        a0 = fmaf(vd, Wod[k * 2 + 0], a0);
        a1 = fmaf(vd, Wod[k * 2 + 1], a1);
        d0 = fmaf(vs, Wos[k * 2 + 0], d0);
        d1 = fmaf(vs, Wos[k * 2 + 1], d1);
    }
    out[(size_t)i * 4 + 0] = a0; out[(size_t)i * 4 + 1] = a1;
    out[(size_t)i * 4 + 2] = d0; out[(size_t)i * 4 + 3] = d1;
}

// ---------------- launch ----------------
extern "C" void kernel_launch(void* const* d_in, const int* in_sizes, int n_in,
                              void* d_out, int out_size, void* d_ws, size_t ws_size,
                              hipStream_t stream)
{
    const float* x      = (const float*)d_in[0];
    const float* x_ft   = (const float*)d_in[1];
    const int*   eidx   = (const int*)d_in[2];
    const float* W_pe   = (const float*)d_in[3];
    const float* b_pe   = (const float*)d_in[4];
    const float* W_gos  = (const float*)d_in[5];
    const float* b_gos  = (const float*)d_in[6];
    const float* W_prot = (const float*)d_in[7];
    const float* b_prot = (const float*)d_in[8];
    const float* W_om0  = (const float*)d_in[9];
    const float* b_om0  = (const float*)d_in[10];
    const float* W_om1  = (const float*)d_in[11];
    const float* b_om1  = (const float*)d_in[12];
    const float* W_om2  = (const float*)d_in[13];
    const float* b_om2  = (const float*)d_in[14];
    const float* W_om3  = (const float*)d_in[15];
    const float* b_om3  = (const float*)d_in[16];
    const float* W_c[3] = {(const float*)d_in[17], (const float*)d_in[21], (const float*)d_in[25]};
    const float* b_c[3] = {(const float*)d_in[18], (const float*)d_in[22], (const float*)d_in[26]};
    const float* W_o[3] = {(const float*)d_in[19], (const float*)d_in[23], (const float*)d_in[27]};
    const float* b_o[3] = {(const float*)d_in[20], (const float*)d_in[24], (const float*)d_in[28]};
    const float* W_lat  = (const float*)d_in[29];
    const float* b_lat  = (const float*)d_in[30];
    const float* W_drug = (const float*)d_in[31];
    const float* b_drug = (const float*)d_in[32];
    const float* W_dis  = (const float*)d_in[33];
    const float* b_dis  = (const float*)d_in[34];
    const float* W_odrug= (const float*)d_in[35];
    const float* b_odrug= (const float*)d_in[36];
    const float* W_odis = (const float*)d_in[37];
    const float* b_odis = (const float*)d_in[38];
    float* out = (float*)d_out;

    const int* e_src = eidx;
    const int* e_dst = eidx + NE;

    // workspace carve-up
    char* p = (char*)d_ws;
    auto alloc = [&](size_t bytes) -> void* {
        void* r = (void*)p;
        p += (bytes + 255) & ~(size_t)255;
        return r;
    };
    float* Wcat    = (float*)alloc((size_t)736 * 384 * 4);
    float* bcat    = (float*)alloc(384 * 4);
    float* Womc    = (float*)alloc((size_t)54 * 384 * 4);
    float* bomc    = (float*)alloc(384 * 4);
    float* deg_inv = (float*)alloc((size_t)NN * 4);
    int*   cnt     = (int*)alloc((size_t)NN * 4);
    int*   ofs     = (int*)alloc((size_t)(NN + 1) * 4);
    int*   cursor  = (int*)alloc((size_t)NN * 4);
    int*   csr_src = (int*)alloc((size_t)NE * 4);
    float* csr_cf  = (float*)alloc((size_t)NE * 4);
    float* h0      = (float*)alloc((size_t)NN * 384 * 4);   // later reused for z
    float* g0      = (float*)alloc((size_t)NN * 384 * 4);
    float* tmpA    = (float*)alloc((size_t)NN * 128 * 4);   // later t_drug
    float* tmpB    = (float*)alloc((size_t)NN * 128 * 4);   // later t_dis
    float* jk      = (float*)alloc((size_t)NN * 768 * 4);
    (void)ws_size; (void)in_sizes; (void)n_in; (void)out_size;

    // 1. pack weights
    {
        int total = 736 * 384 + 54 * 384 + 384;
        pack_weights<<<dim3((total + 255) / 256), dim3(256), 0, stream>>>(
            W_pe, W_gos, W_prot, b_pe, b_gos, b_prot,
            W_om0, W_om1, W_om2, W_om3, b_om0, b_om1, b_om2, b_om3,
            Wcat, bcat, Womc, bomc);
    }
    // 2. degree + CSR
    hipMemsetAsync(cnt, 0, (size_t)NN * 4, stream);
    count_deg<<<dim3((NE + 255) / 256), dim3(256), 0, stream>>>(e_dst, cnt);
    make_deginv<<<dim3((NN + 255) / 256), dim3(256), 0, stream>>>(cnt, deg_inv);
    scan_kernel<<<dim3(1), dim3(256), 0, stream>>>(cnt, ofs, cursor);
    fill_csr<<<dim3((NE + 255) / 256), dim3(256), 0, stream>>>(e_src, e_dst, deg_inv, cursor, csr_src, csr_cf);

    // 3. input MLPs
    launch_gemm(stream, x, 736, Wcat, bcat, h0, NN, 736, 384, true);
    launch_gemm(stream, x_ft, 54, Womc, bomc, g0, NN, 54, 384, true);

    // 4. three GCN layers (dual chain). jk = [h1 h2 h3 g1 g2 g3], stride 768
    // layer 0: inputs h0/g0 (K=384)
    launch_gemm(stream, h0, 384, W_c[0], nullptr, tmpA, NN, 384, 128, false);
    launch_gemm(stream, g0, 384, W_o[0], nullptr, tmpB, NN, 384, 128, false);
    aggregate2<<<dim3(NN), dim3(256), 0, stream>>>(tmpA, tmpB, b_c[0], b_o[0],
        ofs, csr_src, csr_cf, deg_inv, jk, 0, 384);
    // layer 1: inputs jk[:,0:128] / jk[:,384:512] (K=128, lda=768)
    launch_gemm(stream, jk + 0,   768, W_c[1], nullptr, tmpA, NN, 128, 128, false);
    launch_gemm(stream, jk + 384, 768, W_o[1], nullptr, tmpB, NN, 128, 128, false);
    aggregate2<<<dim3(NN), dim3(256), 0, stream>>>(tmpA, tmpB, b_c[1], b_o[1],
        ofs, csr_src, csr_cf, deg_inv, jk, 128, 512);
    // layer 2
    launch_gemm(stream, jk + 128, 768, W_c[2], nullptr, tmpA, NN, 128, 128, false);
    launch_gemm(stream, jk + 512, 768, W_o[2], nullptr, tmpB, NN, 128, 128, false);
    aggregate2<<<dim3(NN), dim3(256), 0, stream>>>(tmpA, tmpB, b_c[2], b_o[2],
        ofs, csr_src, csr_cf, deg_inv, jk, 256, 640);

    // 5. latent: z = act(jk @ W_lat + b_lat)   (reuse h0 buffer)
    float* z = h0;
    launch_gemm(stream, jk, 768, W_lat, b_lat, z, NN, 768, 384, true);

    // 6. heads
    launch_gemm(stream, z, 384, W_drug, b_drug, tmpA, NN, 384, 128, true);
    launch_gemm(stream, z, 384, W_dis,  b_dis,  tmpB, NN, 384, 128, true);
    heads_kernel<<<dim3((NN + 255) / 256), dim3(256), 0, stream>>>(
        tmpA, tmpB, W_odrug, b_odrug, W_odis, b_odis, out);
}

// Round 2
// 722.055 us; speedup vs baseline: 1.5152x; 1.5152x over previous
//
#include <hip/hip_runtime.h>
#include <cstdint>

#define NN 20000
#define NNP 20096            // 157 * 128, padded row count for all activation buffers
#define NE 640000
#define NEG_SLOPE 0.1f

typedef unsigned short ushort_t;
typedef __attribute__((ext_vector_type(8))) short short8;
typedef __attribute__((ext_vector_type(4))) float f32x4;

__device__ __forceinline__ unsigned short f2bf(float f) {
    union { float f; unsigned u; } v; v.f = f;
    unsigned r = v.u + 0x7fffu + ((v.u >> 16) & 1u);
    return (unsigned short)(r >> 16);
}

__device__ __forceinline__ int swz(int r) { return (r ^ (r >> 2)) & 3; }

__device__ __forceinline__ void gld_lds16(const void* g, void* l) {
    __builtin_amdgcn_global_load_lds(
        (const __attribute__((address_space(1))) void*)g,
        (__attribute__((address_space(3))) void*)l,
        16, 0, 0);
}

// ---------------- packed Wt region offsets (elements, bf16) ----------------
// All Wt stored as [M][K] row-major (transposed from source [K][M])
#define O_CAT  0            // 384 x 736
#define O_OM   282624       // 384 x 64 (K padded 54->64 with zeros)
#define O_C0   307200       // 128 x 384
#define O_O0   356352       // 128 x 384
#define O_C1   405504       // 128 x 128
#define O_O1   421888
#define O_C2   438272
#define O_O2   454656
#define O_LAT  471040       // 384 x 768
#define O_DRUG 765952       // 128 x 384
#define O_DIS  815104       // 128 x 384
#define WT_TOTAL 864256

__global__ __launch_bounds__(256) void pack_weights(
    const float* __restrict__ Wpe, const float* __restrict__ Wgos, const float* __restrict__ Wprot,
    const float* __restrict__ bpe, const float* __restrict__ bgos, const float* __restrict__ bprot,
    const float* __restrict__ Wom0, const float* __restrict__ Wom1,
    const float* __restrict__ Wom2, const float* __restrict__ Wom3,
    const float* __restrict__ bom0, const float* __restrict__ bom1,
    const float* __restrict__ bom2, const float* __restrict__ bom3,
    const float* __restrict__ Wc0, const float* __restrict__ Wo0,
    const float* __restrict__ Wc1, const float* __restrict__ Wo1,
    const float* __restrict__ Wc2, const float* __restrict__ Wo2,
    const float* __restrict__ Wlat, const float* __restrict__ Wdrug, const float* __restrict__ Wdis,
    ushort_t* __restrict__ Wt, float* __restrict__ bcat, float* __restrict__ bomc)
{
    int i = blockIdx.x * blockDim.x + threadIdx.x;
    if (i < 282624) {                            // WtCat 384 x 736
        int m = i / 736, k = i % 736;
        float v = (k < 128) ? Wpe[k * 384 + m]
                : (k < 256) ? Wgos[(k - 128) * 384 + m]
                            : Wprot[(k - 256) * 384 + m];
        Wt[O_CAT + i] = f2bf(v);
        return;
    }
    i -= 282624;
    if (i < 24576) {                             // WtOm 384 x 64
        int m = i / 64, k = i % 64;
        float v = (k < 3)  ? Wom0[k * 384 + m]
                : (k < 6)  ? Wom1[(k - 3) * 384 + m]
                : (k < 30) ? Wom2[(k - 6) * 384 + m]
                : (k < 54) ? Wom3[(k - 30) * 384 + m] : 0.f;
        Wt[O_OM + i] = f2bf(v);
        return;
    }
    i -= 24576;
    if (i < 49152) { int m = i / 384, k = i % 384; Wt[O_C0 + i] = f2bf(Wc0[k * 128 + m]); return; }
    i -= 49152;
    if (i < 49152) { int m = i / 384, k = i % 384; Wt[O_O0 + i] = f2bf(Wo0[k * 128 + m]); return; }
    i -= 49152;
    if (i < 16384) { int m = i / 128, k = i % 128; Wt[O_C1 + i] = f2bf(Wc1[k * 128 + m]); return; }
    i -= 16384;
    if (i < 16384) { int m = i / 128, k = i % 128; Wt[O_O1 + i] = f2bf(Wo1[k * 128 + m]); return; }
    i -= 16384;
    if (i < 16384) { int m = i / 128, k = i % 128; Wt[O_C2 + i] = f2bf(Wc2[k * 128 + m]); return; }
    i -= 16384;
    if (i < 16384) { int m = i / 128, k = i % 128; Wt[O_O2 + i] = f2bf(Wo2[k * 128 + m]); return; }
    i -= 16384;
    if (i < 294912) { int m = i / 768, k = i % 768; Wt[O_LAT + i] = f2bf(Wlat[k * 384 + m]); return; }
    i -= 294912;
    if (i < 49152) { int m = i / 384, k = i % 384; Wt[O_DRUG + i] = f2bf(Wdrug[k * 128 + m]); return; }
    i -= 49152;
    if (i < 49152) { int m = i / 384, k = i % 384; Wt[O_DIS + i] = f2bf(Wdis[k * 128 + m]); return; }
    i -= 49152;
    if (i < 384) { bcat[i] = bpe[i] + bgos[i] + bprot[i]; return; }
    i -= 384;
    if (i < 384) { bomc[i] = bom0[i] + bom1[i] + bom2[i] + bom3[i]; return; }
}

// ---------------- input conversions ----------------
__global__ __launch_bounds__(256) void convert_x(const float* __restrict__ x, ushort_t* __restrict__ xb)
{
    int i = blockIdx.x * blockDim.x + threadIdx.x;
    int base = i * 4;
    if (base >= NN * 736) return;
    float4 v = *reinterpret_cast<const float4*>(&x[base]);
    unsigned long long p = (unsigned long long)f2bf(v.x)
                         | ((unsigned long long)f2bf(v.y) << 16)
                         | ((unsigned long long)f2bf(v.z) << 32)
                         | ((unsigned long long)f2bf(v.w) << 48);
    *reinterpret_cast<unsigned long long*>(&xb[base]) = p;
}

__global__ __launch_bounds__(256) void convert_xft(const float* __restrict__ xft, ushort_t* __restrict__ xftb)
{
    int i = blockIdx.x * blockDim.x + threadIdx.x;
    if (i >= NN * 64) return;
    int r = i >> 6, c = i & 63;
    float v = (c < 54) ? xft[r * 54 + c] : 0.f;
    xftb[i] = f2bf(v);
}

// ---------------- degree / CSR ----------------
__global__ __launch_bounds__(256) void count_deg(const int* __restrict__ dst, int* __restrict__ cnt)
{
    int e = blockIdx.x * blockDim.x + threadIdx.x;
    if (e < NE) atomicAdd(&cnt[dst[e]], 1);
}

__global__ __launch_bounds__(256) void make_deginv(const int* __restrict__ cnt, float* __restrict__ deg_inv)
{
    int i = blockIdx.x * blockDim.x + threadIdx.x;
    if (i < NN) deg_inv[i] = rsqrtf((float)cnt[i] + 2.0f);
}

__global__ __launch_bounds__(256) void scan_kernel(const int* __restrict__ cnt,
                                                   int* __restrict__ ofs, int* __restrict__ cursor)
{
    __shared__ int part[256];
    const int t = threadIdx.x;
    const int CH = (NN + 255) / 256;
    int base = t * CH;
    int s = 0;
    for (int i = 0; i < CH; i++) { int idx = base + i; if (idx < NN) s += cnt[idx]; }
    part[t] = s;
    __syncthreads();
    for (int off = 1; off < 256; off <<= 1) {
        int v = (t >= off) ? part[t - off] : 0;
        __syncthreads();
        part[t] += v;
        __syncthreads();
    }
    int run = (t == 0) ? 0 : part[t - 1];
    for (int i = 0; i < CH; i++) {
        int idx = base + i;
        if (idx < NN) { ofs[idx] = run; cursor[idx] = run; run += cnt[idx]; }
    }
    if (t == 255) ofs[NN] = run;
}

__global__ __launch_bounds__(256) void fill_csr(const int* __restrict__ src, const int* __restrict__ dst,
                                                const float* __restrict__ deg_inv,
                                                int* __restrict__ cursor,
                                                int* __restrict__ csr_src, float* __restrict__ csr_cf)
{
    int e = blockIdx.x * blockDim.x + threadIdx.x;
    if (e >= NE) return;
    int s = src[e], d = dst[e];
    int p = atomicAdd(&cursor[d], 1);
    csr_src[p] = s;
    csr_cf[p] = deg_inv[s] * deg_inv[d];
}

// ---------------- bf16 MFMA GEMM ----------------
// C[nrows x M] = [act]( A(bf16, nrows x K, lda) @ Wt(bf16, [M][K])^T [+ bias] )
// BM=128, BK=32, 256 threads = 4 waves in 2x2; BN=128 -> wave 64x64 (4x4 frags),
// BN=64 -> wave 64x32 (4x2 frags). A buffers must have >= gridDim.y*128 rows.
template<int BN, bool BIASACT, bool OUT_BF16>
__global__ __launch_bounds__(256) void mfma_gemm(
    const ushort_t* __restrict__ A, int lda,
    const ushort_t* __restrict__ Wt,
    const float* __restrict__ bias,
    float* __restrict__ Cf, ushort_t* __restrict__ Cb, int ldc,
    int nrows, int K)
{
    constexpr int BM = 128, BK = 32;
    constexpr int NI = (BN == 128) ? 4 : 2;
    __shared__ ushort_t As[BM * BK];
    __shared__ ushort_t Bs[BN * BK];

    const int t = threadIdx.x;
    const int w = t >> 6, lane = t & 63;
    const int row0 = blockIdx.y * BM;
    const int col0 = blockIdx.x * BN;
    const int wr = w >> 1, wc = w & 1;
    const int m16 = lane & 15, quad = lane >> 4;
    const int sr = lane >> 2;       // row within a 16-row staging chunk
    const int pgrp = lane & 3;      // physical 16B group within row

    f32x4 acc[4][NI];
#pragma unroll
    for (int mi = 0; mi < 4; mi++)
#pragma unroll
        for (int ni = 0; ni < NI; ni++) acc[mi][ni] = (f32x4)0.f;

    for (int k0 = 0; k0 < K; k0 += BK) {
        // stage A tile: 128 rows x 32 bf16, 2 issues of 4 waves, 16 rows/wave-issue
#pragma unroll
        for (int p = 0; p < 2; p++) {
            int c = p * 4 + w;
            int r = c * 16 + sr;
            int q = pgrp ^ swz(r);
            gld_lds16(&A[(size_t)(row0 + r) * lda + k0 + q * 8], &As[c * 512]);
        }
        // stage B tile: BN rows x 32 bf16
#pragma unroll
        for (int p = 0; p < BN / 64; p++) {
            int c = p * 4 + w;
            int r = c * 16 + sr;
            int q = pgrp ^ swz(r);
            gld_lds16(&Wt[(size_t)(col0 + r) * K + k0 + q * 8], &Bs[c * 512]);
        }
        __syncthreads();   // drains vmcnt (global_load_lds) + barrier

        short8 af[4], bfr[NI];
#pragma unroll
        for (int mi = 0; mi < 4; mi++) {
            int r = wr * 64 + mi * 16 + m16;
            int p = quad ^ swz(r);
            af[mi] = *reinterpret_cast<const short8*>(&As[r * 32 + p * 8]);
        }
#pragma unroll
        for (int ni = 0; ni < NI; ni++) {
            int n = wc * (NI * 16) + ni * 16 + m16;
            int p = quad ^ swz(n);
            bfr[ni] = *reinterpret_cast<const short8*>(&Bs[n * 32 + p * 8]);
        }
#pragma unroll
        for (int mi = 0; mi < 4; mi++)
#pragma unroll
            for (int ni = 0; ni < NI; ni++)
                acc[mi][ni] = __builtin_amdgcn_mfma_f32_16x16x32_bf16(af[mi], bfr[ni], acc[mi][ni], 0, 0, 0);
        __syncthreads();
    }

    // epilogue: C/D layout col=lane&15, row=quad*4+reg
#pragma unroll
    for (int mi = 0; mi < 4; mi++) {
#pragma unroll
        for (int reg = 0; reg < 4; reg++) {
            int grow = row0 + wr * 64 + mi * 16 + quad * 4 + reg;
            if (grow >= nrows) continue;
#pragma unroll
            for (int ni = 0; ni < NI; ni++) {
                int gcol = col0 + wc * (NI * 16) + ni * 16 + m16;
                float v = acc[mi][ni][reg];
                if constexpr (BIASACT) {
                    v += bias[gcol];
                    v = (v > 0.f) ? v : NEG_SLOPE * v;
                }
                if constexpr (OUT_BF16) Cb[(size_t)grow * ldc + gcol] = f2bf(v);
                else                    Cf[(size_t)grow * ldc + gcol] = v;
            }
        }
    }
}

// ---------------- fused GCN aggregation for both chains ----------------
// block = node i; threads 0..127 -> h chain, 128..255 -> g chain. Gathers fp32,
// accumulates fp32, writes bf16 into jk (stride 768) at hcol/gcol.
__global__ __launch_bounds__(256) void aggregate2(
    const float* __restrict__ hWc, const float* __restrict__ hWo,
    const float* __restrict__ bc, const float* __restrict__ bo,
    const int* __restrict__ ofs, const int* __restrict__ csr_src,
    const float* __restrict__ csr_cf, const float* __restrict__ deg_inv,
    ushort_t* __restrict__ outbase, int hcol, int gcol)
{
    __shared__ int s_src[128];
    __shared__ float s_cf[128];
    const int i = blockIdx.x;
    const int t = threadIdx.x;
    const int f = t & 127;
    const bool isH = (t < 128);
    const float* __restrict__ hW = isH ? hWc : hWo;
    const int start = ofs[i], end = ofs[i + 1];
    const float di = deg_inv[i];
    float acc = hW[(size_t)i * 128 + f] * (2.0f * di * di);
    for (int base = start; base < end; base += 128) {
        int n = end - base; if (n > 128) n = 128;
        __syncthreads();
        if (t < n) { s_src[t] = csr_src[base + t]; s_cf[t] = csr_cf[base + t]; }
        __syncthreads();
        int e = 0;
        for (; e + 4 <= n; e += 4) {
            int s0 = s_src[e], s1 = s_src[e + 1], s2 = s_src[e + 2], s3 = s_src[e + 3];
            float c0 = s_cf[e], c1 = s_cf[e + 1], c2 = s_cf[e + 2], c3 = s_cf[e + 3];
            float v0 = hW[(size_t)s0 * 128 + f];
            float v1 = hW[(size_t)s1 * 128 + f];
            float v2 = hW[(size_t)s2 * 128 + f];
            float v3 = hW[(size_t)s3 * 128 + f];
            acc = fmaf(v0, c0, acc); acc = fmaf(v1, c1, acc);
            acc = fmaf(v2, c2, acc); acc = fmaf(v3, c3, acc);
        }
        for (; e < n; e++) acc = fmaf(hW[(size_t)s_src[e] * 128 + f], s_cf[e], acc);
    }
    float b = isH ? bc[f] : bo[f];
    float v = acc + b;
    v = (v > 0.f) ? v : NEG_SLOPE * v;
    int col = isH ? hcol : gcol;
    outbase[(size_t)i * 768 + col + f] = f2bf(v);
}

// ---------------- final 2-wide heads ----------------
__global__ __launch_bounds__(256) void heads_kernel(
    const float* __restrict__ td, const float* __restrict__ ts,
    const float* __restrict__ Wod, const float* __restrict__ bod,
    const float* __restrict__ Wos, const float* __restrict__ bos,
    float* __restrict__ out)
{
    int i = blockIdx.x * blockDim.x + threadIdx.x;
    if (i >= NN) return;
    float a0 = bod[0], a1 = bod[1], d0 = bos[0], d1 = bos[1];
    for (int k = 0; k < 128; k++) {
        float vd = td[(size_t)i * 128 + k];
        float vs = ts[(size_t)i * 128 + k];
        a0 = fmaf(vd, Wod[k * 2 + 0], a0);
        a1 = fmaf(vd, Wod[k * 2 + 1], a1);
        d0 = fmaf(vs, Wos[k * 2 + 0], d0);
        d1 = fmaf(vs, Wos[k * 2 + 1], d1);
    }
    out[(size_t)i * 4 + 0] = a0; out[(size_t)i * 4 + 1] = a1;
    out[(size_t)i * 4 + 2] = d0; out[(size_t)i * 4 + 3] = d1;
}

// ---------------- launch ----------------
template<int BN, bool BIASACT, bool OUT_BF16>
static void launch_mfma(hipStream_t st, const ushort_t* A, int lda, const ushort_t* Wt,
                        const float* bias, float* Cf, ushort_t* Cb, int ldc, int K, int M)
{
    dim3 g(M / BN, NNP / 128), b(256);
    mfma_gemm<BN, BIASACT, OUT_BF16><<<g, b, 0, st>>>(A, lda, Wt, bias, Cf, Cb, ldc, NN, K);
}

extern "C" void kernel_launch(void* const* d_in, const int* in_sizes, int n_in,
                              void* d_out, int out_size, void* d_ws, size_t ws_size,
                              hipStream_t stream)
{
    const float* x      = (const float*)d_in[0];
    const float* x_ft   = (const float*)d_in[1];
    const int*   eidx   = (const int*)d_in[2];
    const float* W_pe   = (const float*)d_in[3];
    const float* b_pe   = (const float*)d_in[4];
    const float* W_gos  = (const float*)d_in[5];
    const float* b_gos  = (const float*)d_in[6];
    const float* W_prot = (const float*)d_in[7];
    const float* b_prot = (const float*)d_in[8];
    const float* W_om0  = (const float*)d_in[9];
    const float* b_om0  = (const float*)d_in[10];
    const float* W_om1  = (const float*)d_in[11];
    const float* b_om1  = (const float*)d_in[12];
    const float* W_om2  = (const float*)d_in[13];
    const float* b_om2  = (const float*)d_in[14];
    const float* W_om3  = (const float*)d_in[15];
    const float* b_om3  = (const float*)d_in[16];
    const float* W_c[3] = {(const float*)d_in[17], (const float*)d_in[21], (const float*)d_in[25]};
    const float* b_c[3] = {(const float*)d_in[18], (const float*)d_in[22], (const float*)d_in[26]};
    const float* W_o[3] = {(const float*)d_in[19], (const float*)d_in[23], (const float*)d_in[27]};
    const float* b_o[3] = {(const float*)d_in[20], (const float*)d_in[24], (const float*)d_in[28]};
    const float* W_lat  = (const float*)d_in[29];
    const float* b_lat  = (const float*)d_in[30];
    const float* W_drug = (const float*)d_in[31];
    const float* b_drug = (const float*)d_in[32];
    const float* W_dis  = (const float*)d_in[33];
    const float* b_dis  = (const float*)d_in[34];
    const float* W_odrug= (const float*)d_in[35];
    const float* b_odrug= (const float*)d_in[36];
    const float* W_odis = (const float*)d_in[37];
    const float* b_odis = (const float*)d_in[38];
    float* out = (float*)d_out;

    const int* e_src = eidx;
    const int* e_dst = eidx + NE;

    char* p = (char*)d_ws;
    auto alloc = [&](size_t bytes) -> void* {
        void* r = (void*)p;
        p += (bytes + 255) & ~(size_t)255;
        return r;
    };
    ushort_t* Wt    = (ushort_t*)alloc((size_t)WT_TOTAL * 2);
    float* bcat     = (float*)alloc(384 * 4);
    float* bomc     = (float*)alloc(384 * 4);
    float* deg_inv  = (float*)alloc((size_t)NN * 4);
    int*   cnt      = (int*)alloc((size_t)NN * 4);
    int*   ofs      = (int*)alloc((size_t)(NN + 1) * 4);
    int*   cursor   = (int*)alloc((size_t)NN * 4);
    int*   csr_src  = (int*)alloc((size_t)NE * 4);
    float* csr_cf   = (float*)alloc((size_t)NE * 4);
    ushort_t* xb    = (ushort_t*)alloc((size_t)NNP * 736 * 2);
    ushort_t* xftb  = (ushort_t*)alloc((size_t)NNP * 64 * 2);
    ushort_t* h0b   = (ushort_t*)alloc((size_t)NNP * 384 * 2);
    ushort_t* g0b   = (ushort_t*)alloc((size_t)NNP * 384 * 2);
    ushort_t* jkb   = (ushort_t*)alloc((size_t)NNP * 768 * 2);
    ushort_t* zb    = (ushort_t*)alloc((size_t)NNP * 384 * 2);
    float* tmpA     = (float*)alloc((size_t)NNP * 128 * 4);
    float* tmpB     = (float*)alloc((size_t)NNP * 128 * 4);
    (void)ws_size; (void)in_sizes; (void)n_in; (void)out_size;

    // 1. pack + transpose weights to bf16 [M][K]
    {
        int total = WT_TOTAL + 768;
        pack_weights<<<dim3((total + 255) / 256), dim3(256), 0, stream>>>(
            W_pe, W_gos, W_prot, b_pe, b_gos, b_prot,
            W_om0, W_om1, W_om2, W_om3, b_om0, b_om1, b_om2, b_om3,
            W_c[0], W_o[0], W_c[1], W_o[1], W_c[2], W_o[2],
            W_lat, W_drug, W_dis, Wt, bcat, bomc);
    }
    // 2. convert inputs to bf16
    convert_x<<<dim3((NN * 736 / 4 + 255) / 256), dim3(256), 0, stream>>>(x, xb);
    convert_xft<<<dim3((NN * 64 + 255) / 256), dim3(256), 0, stream>>>(x_ft, xftb);

    // 3. degree + CSR
    hipMemsetAsync(cnt, 0, (size_t)NN * 4, stream);
    count_deg<<<dim3((NE + 255) / 256), dim3(256), 0, stream>>>(e_dst, cnt);
    make_deginv<<<dim3((NN + 255) / 256), dim3(256), 0, stream>>>(cnt, deg_inv);
    scan_kernel<<<dim3(1), dim3(256), 0, stream>>>(cnt, ofs, cursor);
    fill_csr<<<dim3((NE + 255) / 256), dim3(256), 0, stream>>>(e_src, e_dst, deg_inv, cursor, csr_src, csr_cf);

    // 4. input MLPs (bf16 MFMA, bf16 out)
    launch_mfma<128, true, true>(stream, xb,   736, Wt + O_CAT, bcat, nullptr, h0b, 384, 736, 384);
    launch_mfma<128, true, true>(stream, xftb,  64, Wt + O_OM,  bomc, nullptr, g0b, 384,  64, 384);

    // 5. three GCN layers. jkb = bf16 [h1 h2 h3 g1 g2 g3], stride 768
    launch_mfma<64, false, false>(stream, h0b, 384, Wt + O_C0, nullptr, tmpA, nullptr, 128, 384, 128);
    launch_mfma<64, false, false>(stream, g0b, 384, Wt + O_O0, nullptr, tmpB, nullptr, 128, 384, 128);
    aggregate2<<<dim3(NN), dim3(256), 0, stream>>>(tmpA, tmpB, b_c[0], b_o[0],
        ofs, csr_src, csr_cf, deg_inv, jkb, 0, 384);

    launch_mfma<64, false, false>(stream, jkb + 0,   768, Wt + O_C1, nullptr, tmpA, nullptr, 128, 128, 128);
    launch_mfma<64, false, false>(stream, jkb + 384, 768, Wt + O_O1, nullptr, tmpB, nullptr, 128, 128, 128);
    aggregate2<<<dim3(NN), dim3(256), 0, stream>>>(tmpA, tmpB, b_c[1], b_o[1],
        ofs, csr_src, csr_cf, deg_inv, jkb, 128, 512);

    launch_mfma<64, false, false>(stream, jkb + 128, 768, Wt + O_C2, nullptr, tmpA, nullptr, 128, 128, 128);
    launch_mfma<64, false, false>(stream, jkb + 512, 768, Wt + O_O2, nullptr, tmpB, nullptr, 128, 128, 128);
    aggregate2<<<dim3(NN), dim3(256), 0, stream>>>(tmpA, tmpB, b_c[2], b_o[2],
        ofs, csr_src, csr_cf, deg_inv, jkb, 256, 640);

    // 6. latent: zb = act(jkb @ W_lat + b_lat), bf16
    launch_mfma<128, true, true>(stream, jkb, 768, Wt + O_LAT, b_lat, nullptr, zb, 384, 768, 384);

    // 7. heads: fp32 out for final reduce
    launch_mfma<64, true, false>(stream, zb, 384, Wt + O_DRUG, b_drug, tmpA, nullptr, 128, 384, 128);
    launch_mfma<64, true, false>(stream, zb, 384, Wt + O_DIS,  b_dis,  tmpB, nullptr, 128, 384, 128);
    heads_kernel<<<dim3((NN + 255) / 256), dim3(256), 0, stream>>>(
        tmpA, tmpB, W_odrug, b_odrug, W_odis, b_odis, out);
}

// Round 3
// 674.978 us; speedup vs baseline: 1.6208x; 1.0697x over previous
//
#include <hip/hip_runtime.h>
#include <cstdint>

#define NN 20000
#define NNP 20096            // 157 * 128, padded row count for all activation buffers
#define NE 640000
#define NEG_SLOPE 0.1f

typedef unsigned short ushort_t;
typedef __attribute__((ext_vector_type(8))) short short8;
typedef __attribute__((ext_vector_type(4))) float f32x4;

__device__ __forceinline__ unsigned short f2bf(float f) {
    union { float f; unsigned u; } v; v.f = f;
    unsigned r = v.u + 0x7fffu + ((v.u >> 16) & 1u);
    return (unsigned short)(r >> 16);
}
__device__ __forceinline__ float bflo(unsigned u) { return __uint_as_float(u << 16); }
__device__ __forceinline__ float bfhi(unsigned u) { return __uint_as_float(u & 0xffff0000u); }

__device__ __forceinline__ int swz(int r) { return (r ^ (r >> 2)) & 3; }

__device__ __forceinline__ void gld_lds16(const void* g, void* l) {
    __builtin_amdgcn_global_load_lds(
        (const __attribute__((address_space(1))) void*)g,
        (__attribute__((address_space(3))) void*)l,
        16, 0, 0);
}

// ---------------- packed Wt region offsets (elements, bf16) ----------------
// All Wt stored as [M][K] row-major (transposed from source [K][M])
#define O_CAT   0            // 384 x 736
#define O_OM    282624       // 384 x 64 (K padded 54->64 with zeros)
#define O_C0    307200       // 128 x 384
#define O_O0    356352       // 128 x 384
#define O_C1    405504       // 128 x 128
#define O_O1    421888
#define O_C2    438272
#define O_O2    454656
#define O_LAT   471040       // 384 x 768
#define O_HEADS 765952       // 256 x 384  (rows 0..127 = drug, 128..255 = dis)
#define WT_TOTAL 864256

__global__ __launch_bounds__(256) void pack_weights(
    const float* __restrict__ Wpe, const float* __restrict__ Wgos, const float* __restrict__ Wprot,
    const float* __restrict__ bpe, const float* __restrict__ bgos, const float* __restrict__ bprot,
    const float* __restrict__ Wom0, const float* __restrict__ Wom1,
    const float* __restrict__ Wom2, const float* __restrict__ Wom3,
    const float* __restrict__ bom0, const float* __restrict__ bom1,
    const float* __restrict__ bom2, const float* __restrict__ bom3,
    const float* __restrict__ Wc0, const float* __restrict__ Wo0,
    const float* __restrict__ Wc1, const float* __restrict__ Wo1,
    const float* __restrict__ Wc2, const float* __restrict__ Wo2,
    const float* __restrict__ Wlat,
    const float* __restrict__ Wdrug, const float* __restrict__ Wdis,
    const float* __restrict__ bdrug, const float* __restrict__ bdis,
    ushort_t* __restrict__ Wt, float* __restrict__ bcat, float* __restrict__ bomc,
    float* __restrict__ bheads)
{
    int i = blockIdx.x * blockDim.x + threadIdx.x;
    if (i < 282624) {                            // WtCat 384 x 736
        int m = i / 736, k = i % 736;
        float v = (k < 128) ? Wpe[k * 384 + m]
                : (k < 256) ? Wgos[(k - 128) * 384 + m]
                            : Wprot[(k - 256) * 384 + m];
        Wt[O_CAT + i] = f2bf(v);
        return;
    }
    i -= 282624;
    if (i < 24576) {                             // WtOm 384 x 64
        int m = i / 64, k = i % 64;
        float v = (k < 3)  ? Wom0[k * 384 + m]
                : (k < 6)  ? Wom1[(k - 3) * 384 + m]
                : (k < 30) ? Wom2[(k - 6) * 384 + m]
                : (k < 54) ? Wom3[(k - 30) * 384 + m] : 0.f;
        Wt[O_OM + i] = f2bf(v);
        return;
    }
    i -= 24576;
    if (i < 49152) { int m = i / 384, k = i % 384; Wt[O_C0 + i] = f2bf(Wc0[k * 128 + m]); return; }
    i -= 49152;
    if (i < 49152) { int m = i / 384, k = i % 384; Wt[O_O0 + i] = f2bf(Wo0[k * 128 + m]); return; }
    i -= 49152;
    if (i < 16384) { int m = i / 128, k = i % 128; Wt[O_C1 + i] = f2bf(Wc1[k * 128 + m]); return; }
    i -= 16384;
    if (i < 16384) { int m = i / 128, k = i % 128; Wt[O_O1 + i] = f2bf(Wo1[k * 128 + m]); return; }
    i -= 16384;
    if (i < 16384) { int m = i / 128, k = i % 128; Wt[O_C2 + i] = f2bf(Wc2[k * 128 + m]); return; }
    i -= 16384;
    if (i < 16384) { int m = i / 128, k = i % 128; Wt[O_O2 + i] = f2bf(Wo2[k * 128 + m]); return; }
    i -= 16384;
    if (i < 294912) { int m = i / 768, k = i % 768; Wt[O_LAT + i] = f2bf(Wlat[k * 384 + m]); return; }
    i -= 294912;
    if (i < 98304) {                             // heads 256 x 384
        int m = i / 384, k = i % 384;
        float v = (m < 128) ? Wdrug[k * 128 + m] : Wdis[k * 128 + (m - 128)];
        Wt[O_HEADS + i] = f2bf(v);
        return;
    }
    i -= 98304;
    if (i < 384) { bcat[i] = bpe[i] + bgos[i] + bprot[i]; return; }
    i -= 384;
    if (i < 384) { bomc[i] = bom0[i] + bom1[i] + bom2[i] + bom3[i]; return; }
    i -= 384;
    if (i < 256) { bheads[i] = (i < 128) ? bdrug[i] : bdis[i - 128]; return; }
}

// ---------------- input conversions ----------------
__global__ __launch_bounds__(256) void convert_x(const float* __restrict__ x, ushort_t* __restrict__ xb)
{
    int i = blockIdx.x * blockDim.x + threadIdx.x;
    int base = i * 4;
    if (base >= NN * 736) return;
    float4 v = *reinterpret_cast<const float4*>(&x[base]);
    unsigned long long p = (unsigned long long)f2bf(v.x)
                         | ((unsigned long long)f2bf(v.y) << 16)
                         | ((unsigned long long)f2bf(v.z) << 32)
                         | ((unsigned long long)f2bf(v.w) << 48);
    *reinterpret_cast<unsigned long long*>(&xb[base]) = p;
}

__global__ __launch_bounds__(256) void convert_xft(const float* __restrict__ xft, ushort_t* __restrict__ xftb)
{
    int i = blockIdx.x * blockDim.x + threadIdx.x;
    if (i >= NN * 64) return;
    int r = i >> 6, c = i & 63;
    float v = (c < 54) ? xft[r * 54 + c] : 0.f;
    xftb[i] = f2bf(v);
}

// ---------------- degree / CSR ----------------
__global__ __launch_bounds__(256) void count_deg(const int* __restrict__ dst, int* __restrict__ cnt)
{
    int e = blockIdx.x * blockDim.x + threadIdx.x;
    if (e < NE) atomicAdd(&cnt[dst[e]], 1);
}

__global__ __launch_bounds__(256) void make_deginv(const int* __restrict__ cnt, float* __restrict__ deg_inv)
{
    int i = blockIdx.x * blockDim.x + threadIdx.x;
    if (i < NN) deg_inv[i] = rsqrtf((float)cnt[i] + 2.0f);
}

__global__ __launch_bounds__(256) void scan_kernel(const int* __restrict__ cnt,
                                                   int* __restrict__ ofs, int* __restrict__ cursor)
{
    __shared__ int part[256];
    const int t = threadIdx.x;
    const int CH = (NN + 255) / 256;
    int base = t * CH;
    int s = 0;
    for (int i = 0; i < CH; i++) { int idx = base + i; if (idx < NN) s += cnt[idx]; }
    part[t] = s;
    __syncthreads();
    for (int off = 1; off < 256; off <<= 1) {
        int v = (t >= off) ? part[t - off] : 0;
        __syncthreads();
        part[t] += v;
        __syncthreads();
    }
    int run = (t == 0) ? 0 : part[t - 1];
    for (int i = 0; i < CH; i++) {
        int idx = base + i;
        if (idx < NN) { ofs[idx] = run; cursor[idx] = run; run += cnt[idx]; }
    }
    if (t == 255) ofs[NN] = run;
}

__global__ __launch_bounds__(256) void fill_csr(const int* __restrict__ src, const int* __restrict__ dst,
                                                const float* __restrict__ deg_inv,
                                                int* __restrict__ cursor,
                                                int* __restrict__ csr_src, float* __restrict__ csr_cf)
{
    int e = blockIdx.x * blockDim.x + threadIdx.x;
    if (e >= NE) return;
    int s = src[e], d = dst[e];
    int p = atomicAdd(&cursor[d], 1);
    csr_src[p] = s;
    csr_cf[p] = deg_inv[s] * deg_inv[d];
}

// ---------------- bf16 MFMA GEMM body ----------------
// C[nrows x M] = [act]( A(bf16, nrows x K, lda) @ Wt(bf16, [M][K])^T [+ bias] )
// BM=128, BK=32, 256 threads = 4 waves 2x2. A buffers must have >= gridDim.y*128 rows.
template<int BN, bool BIASACT, bool OUT_BF16>
__device__ __forceinline__ void gemm_body(
    ushort_t* As, ushort_t* Bs,
    const ushort_t* __restrict__ A, int lda,
    const ushort_t* __restrict__ Wt,
    const float* __restrict__ bias,
    float* __restrict__ Cf, ushort_t* __restrict__ Cb, int ldc,
    int nrows, int K, int row0, int col0)
{
    constexpr int BK = 32;
    constexpr int NI = (BN == 128) ? 4 : 2;

    const int t = threadIdx.x;
    const int w = t >> 6, lane = t & 63;
    const int wr = w >> 1, wc = w & 1;
    const int m16 = lane & 15, quad = lane >> 4;
    const int sr = lane >> 2;       // row within a 16-row staging chunk
    const int pgrp = lane & 3;      // physical 16B group within row

    f32x4 acc[4][NI];
#pragma unroll
    for (int mi = 0; mi < 4; mi++)
#pragma unroll
        for (int ni = 0; ni < NI; ni++) acc[mi][ni] = (f32x4)0.f;

    for (int k0 = 0; k0 < K; k0 += BK) {
#pragma unroll
        for (int p = 0; p < 2; p++) {
            int c = p * 4 + w;
            int r = c * 16 + sr;
            int q = pgrp ^ swz(r);
            gld_lds16(&A[(size_t)(row0 + r) * lda + k0 + q * 8], &As[c * 512]);
        }
#pragma unroll
        for (int p = 0; p < BN / 64; p++) {
            int c = p * 4 + w;
            int r = c * 16 + sr;
            int q = pgrp ^ swz(r);
            gld_lds16(&Wt[(size_t)(col0 + r) * K + k0 + q * 8], &Bs[c * 512]);
        }
        __syncthreads();

        short8 af[4], bfr[NI];
#pragma unroll
        for (int mi = 0; mi < 4; mi++) {
            int r = wr * 64 + mi * 16 + m16;
            int p = quad ^ swz(r);
            af[mi] = *reinterpret_cast<const short8*>(&As[r * 32 + p * 8]);
        }
#pragma unroll
        for (int ni = 0; ni < NI; ni++) {
            int n = wc * (NI * 16) + ni * 16 + m16;
            int p = quad ^ swz(n);
            bfr[ni] = *reinterpret_cast<const short8*>(&Bs[n * 32 + p * 8]);
        }
#pragma unroll
        for (int mi = 0; mi < 4; mi++)
#pragma unroll
            for (int ni = 0; ni < NI; ni++)
                acc[mi][ni] = __builtin_amdgcn_mfma_f32_16x16x32_bf16(af[mi], bfr[ni], acc[mi][ni], 0, 0, 0);
        __syncthreads();
    }

    // epilogue: C/D layout col=lane&15, row=quad*4+reg
#pragma unroll
    for (int mi = 0; mi < 4; mi++) {
#pragma unroll
        for (int reg = 0; reg < 4; reg++) {
            int grow = row0 + wr * 64 + mi * 16 + quad * 4 + reg;
            if (grow >= nrows) continue;
#pragma unroll
            for (int ni = 0; ni < NI; ni++) {
                int gcol = col0 + wc * (NI * 16) + ni * 16 + m16;
                float v = acc[mi][ni][reg];
                if constexpr (BIASACT) {
                    v += bias[gcol];
                    v = (v > 0.f) ? v : NEG_SLOPE * v;
                }
                if constexpr (OUT_BF16) Cb[(size_t)grow * ldc + gcol] = f2bf(v);
                else                    Cf[(size_t)grow * ldc + gcol] = v;
            }
        }
    }
}

template<int BN, bool BIASACT, bool OUT_BF16>
__global__ __launch_bounds__(256) void mfma_gemm(
    const ushort_t* __restrict__ A, int lda,
    const ushort_t* __restrict__ Wt,
    const float* __restrict__ bias,
    float* __restrict__ Cf, ushort_t* __restrict__ Cb, int ldc,
    int nrows, int K)
{
    __shared__ ushort_t As[128 * 32];
    __shared__ ushort_t Bs[BN * 32];
    gemm_body<BN, BIASACT, OUT_BF16>(As, Bs, A, lda, Wt, bias, Cf, Cb, ldc, nrows, K,
                                     blockIdx.y * 128, blockIdx.x * BN);
}

// z-batched dual GEMM (both GCN chains in one launch), BN=64, no bias, bf16 out
__global__ __launch_bounds__(256) void mfma_gemm_dual(
    const ushort_t* __restrict__ A0, const ushort_t* __restrict__ A1, int lda,
    const ushort_t* __restrict__ W0, const ushort_t* __restrict__ W1,
    ushort_t* __restrict__ C0, ushort_t* __restrict__ C1, int ldc,
    int nrows, int K)
{
    __shared__ ushort_t As[128 * 32];
    __shared__ ushort_t Bs[64 * 32];
    const ushort_t* A  = blockIdx.z ? A1 : A0;
    const ushort_t* Wt = blockIdx.z ? W1 : W0;
    ushort_t*       Cb = blockIdx.z ? C1 : C0;
    gemm_body<64, false, true>(As, Bs, A, lda, Wt, nullptr, nullptr, Cb, ldc, nrows, K,
                               blockIdx.y * 128, blockIdx.x * 64);
}

// ---------------- GCN aggregation, L2-resident slices ----------------
// grid.x = 4*NN, slice-major: slice = bx/NN in {0..3} = (chain<<1)|half.
// Each slice gathers a 2.56 MB bf16 table slice (64 feats = 128 B/edge, one
// cache line) -> fits per-XCD L2. 32 edge-groups x 8 feat-octet lanes.
__global__ __launch_bounds__(256) void aggregate_slices(
    const ushort_t* __restrict__ tabA, const ushort_t* __restrict__ tabB,
    const float* __restrict__ bc, const float* __restrict__ bo,
    const int* __restrict__ ofs, const int* __restrict__ csr_src,
    const float* __restrict__ csr_cf, const float* __restrict__ deg_inv,
    ushort_t* __restrict__ outb, int hcol, int gcol)
{
    const int bx = blockIdx.x;
    const int slice = bx / NN;
    const int i = bx - slice * NN;
    const int chain = slice >> 1, half = slice & 1;
    const ushort_t* __restrict__ tab = chain ? tabB : tabA;
    const float* __restrict__ bias = chain ? bo : bc;

    const int t = threadIdx.x;
    const int grp = t >> 3;        // 0..31 edge group
    const int l = t & 7;           // feature octet (feats l*8 .. l*8+7 of the half)

    __shared__ int s_src[64];
    __shared__ float s_cf[64];
    __shared__ float red[32][65];

    const int start = ofs[i], end = ofs[i + 1];
    const size_t halfoff = (size_t)half * 64;

    float acc[8];
#pragma unroll
    for (int q = 0; q < 8; q++) acc[q] = 0.f;

    if (grp == 0) {   // self term
        float di = deg_inv[i];
        float c = 2.f * di * di;
        uint4 pv = *reinterpret_cast<const uint4*>(&tab[(size_t)i * 128 + halfoff + l * 8]);
        acc[0] = bflo(pv.x) * c; acc[1] = bfhi(pv.x) * c;
        acc[2] = bflo(pv.y) * c; acc[3] = bfhi(pv.y) * c;
        acc[4] = bflo(pv.z) * c; acc[5] = bfhi(pv.z) * c;
        acc[6] = bflo(pv.w) * c; acc[7] = bfhi(pv.w) * c;
    }

    for (int base = start; base < end; base += 64) {
        int n = end - base; if (n > 64) n = 64;
        __syncthreads();
        if (t < n) { s_src[t] = csr_src[base + t]; s_cf[t] = csr_cf[base + t]; }
        __syncthreads();
#pragma unroll
        for (int e0 = 0; e0 < 64; e0 += 32) {
            int e = e0 + grp;
            if (e < n) {
                int s = s_src[e]; float cf = s_cf[e];
                uint4 pv = *reinterpret_cast<const uint4*>(&tab[(size_t)s * 128 + halfoff + l * 8]);
                acc[0] = fmaf(bflo(pv.x), cf, acc[0]);
                acc[1] = fmaf(bfhi(pv.x), cf, acc[1]);
                acc[2] = fmaf(bflo(pv.y), cf, acc[2]);
                acc[3] = fmaf(bfhi(pv.y), cf, acc[3]);
                acc[4] = fmaf(bflo(pv.z), cf, acc[4]);
                acc[5] = fmaf(bfhi(pv.z), cf, acc[5]);
                acc[6] = fmaf(bflo(pv.w), cf, acc[6]);
                acc[7] = fmaf(bfhi(pv.w), cf, acc[7]);
            }
        }
    }
    __syncthreads();
#pragma unroll
    for (int q = 0; q < 8; q++) red[grp][l * 8 + q] = acc[q];
    __syncthreads();
    if (t < 64) {
        float v = 0.f;
#pragma unroll
        for (int g = 0; g < 32; g++) v += red[g][t];
        v += bias[halfoff + t];
        v = (v > 0.f) ? v : NEG_SLOPE * v;
        int col = (chain ? gcol : hcol) + (int)halfoff + t;
        outb[(size_t)i * 768 + col] = f2bf(v);
    }
}

// ---------------- final 2-wide heads: wave per node ----------------
__global__ __launch_bounds__(256) void heads_kernel(
    const float* __restrict__ tmpH,
    const float* __restrict__ Wod, const float* __restrict__ bod,
    const float* __restrict__ Wos, const float* __restrict__ bos,
    float* __restrict__ out)
{
    int w = threadIdx.x >> 6, lane = threadIdx.x & 63;
    int i = blockIdx.x * 4 + w;
    if (i >= NN) return;
    float a0 = 0.f, a1 = 0.f, d0 = 0.f, d1 = 0.f;
#pragma unroll
    for (int p = 0; p < 2; p++) {
        int k = lane + p * 64;
        float vd = tmpH[(size_t)i * 256 + k];
        float vs = tmpH[(size_t)i * 256 + 128 + k];
        a0 = fmaf(vd, Wod[k * 2 + 0], a0);
        a1 = fmaf(vd, Wod[k * 2 + 1], a1);
        d0 = fmaf(vs, Wos[k * 2 + 0], d0);
        d1 = fmaf(vs, Wos[k * 2 + 1], d1);
    }
    for (int off = 32; off; off >>= 1) {
        a0 += __shfl_down(a0, off);
        a1 += __shfl_down(a1, off);
        d0 += __shfl_down(d0, off);
        d1 += __shfl_down(d1, off);
    }
    if (lane == 0) {
        out[(size_t)i * 4 + 0] = a0 + bod[0];
        out[(size_t)i * 4 + 1] = a1 + bod[1];
        out[(size_t)i * 4 + 2] = d0 + bos[0];
        out[(size_t)i * 4 + 3] = d1 + bos[1];
    }
}

// ---------------- launch ----------------
extern "C" void kernel_launch(void* const* d_in, const int* in_sizes, int n_in,
                              void* d_out, int out_size, void* d_ws, size_t ws_size,
                              hipStream_t stream)
{
    const float* x      = (const float*)d_in[0];
    const float* x_ft   = (const float*)d_in[1];
    const int*   eidx   = (const int*)d_in[2];
    const float* W_pe   = (const float*)d_in[3];
    const float* b_pe   = (const float*)d_in[4];
    const float* W_gos  = (const float*)d_in[5];
    const float* b_gos  = (const float*)d_in[6];
    const float* W_prot = (const float*)d_in[7];
    const float* b_prot = (const float*)d_in[8];
    const float* W_om0  = (const float*)d_in[9];
    const float* b_om0  = (const float*)d_in[10];
    const float* W_om1  = (const float*)d_in[11];
    const float* b_om1  = (const float*)d_in[12];
    const float* W_om2  = (const float*)d_in[13];
    const float* b_om2  = (const float*)d_in[14];
    const float* W_om3  = (const float*)d_in[15];
    const float* b_om3  = (const float*)d_in[16];
    const float* W_c[3] = {(const float*)d_in[17], (const float*)d_in[21], (const float*)d_in[25]};
    const float* b_c[3] = {(const float*)d_in[18], (const float*)d_in[22], (const float*)d_in[26]};
    const float* W_o[3] = {(const float*)d_in[19], (const float*)d_in[23], (const float*)d_in[27]};
    const float* b_o[3] = {(const float*)d_in[20], (const float*)d_in[24], (const float*)d_in[28]};
    const float* W_lat  = (const float*)d_in[29];
    const float* b_lat  = (const float*)d_in[30];
    const float* W_drug = (const float*)d_in[31];
    const float* b_drug = (const float*)d_in[32];
    const float* W_dis  = (const float*)d_in[33];
    const float* b_dis  = (const float*)d_in[34];
    const float* W_odrug= (const float*)d_in[35];
    const float* b_odrug= (const float*)d_in[36];
    const float* W_odis = (const float*)d_in[37];
    const float* b_odis = (const float*)d_in[38];
    float* out = (float*)d_out;

    const int* e_src = eidx;
    const int* e_dst = eidx + NE;

    char* p = (char*)d_ws;
    auto alloc = [&](size_t bytes) -> void* {
        void* r = (void*)p;
        p += (bytes + 255) & ~(size_t)255;
        return r;
    };
    ushort_t* Wt    = (ushort_t*)alloc((size_t)WT_TOTAL * 2);
    float* bcat     = (float*)alloc(384 * 4);
    float* bomc     = (float*)alloc(384 * 4);
    float* bheads   = (float*)alloc(256 * 4);
    float* deg_inv  = (float*)alloc((size_t)NN * 4);
    int*   cnt      = (int*)alloc((size_t)NN * 4);
    int*   ofs      = (int*)alloc((size_t)(NN + 1) * 4);
    int*   cursor   = (int*)alloc((size_t)NN * 4);
    int*   csr_src  = (int*)alloc((size_t)NE * 4);
    float* csr_cf   = (float*)alloc((size_t)NE * 4);
    ushort_t* xb    = (ushort_t*)alloc((size_t)NNP * 736 * 2);
    ushort_t* xftb  = (ushort_t*)alloc((size_t)NNP * 64 * 2);
    ushort_t* h0b   = (ushort_t*)alloc((size_t)NNP * 384 * 2);
    ushort_t* g0b   = (ushort_t*)alloc((size_t)NNP * 384 * 2);
    ushort_t* jkb   = (ushort_t*)alloc((size_t)NNP * 768 * 2);
    ushort_t* zb    = (ushort_t*)alloc((size_t)NNP * 384 * 2);
    ushort_t* tmpAb = (ushort_t*)alloc((size_t)NNP * 128 * 2);
    ushort_t* tmpBb = (ushort_t*)alloc((size_t)NNP * 128 * 2);
    float* tmpH     = (float*)alloc((size_t)NNP * 256 * 4);
    (void)ws_size; (void)in_sizes; (void)n_in; (void)out_size;

    // 1. pack + transpose weights to bf16 [M][K]
    {
        int total = WT_TOTAL + 384 + 384 + 256;
        pack_weights<<<dim3((total + 255) / 256), dim3(256), 0, stream>>>(
            W_pe, W_gos, W_prot, b_pe, b_gos, b_prot,
            W_om0, W_om1, W_om2, W_om3, b_om0, b_om1, b_om2, b_om3,
            W_c[0], W_o[0], W_c[1], W_o[1], W_c[2], W_o[2],
            W_lat, W_drug, W_dis, b_drug, b_dis, Wt, bcat, bomc, bheads);
    }
    // 2. convert inputs to bf16
    convert_x<<<dim3((NN * 736 / 4 + 255) / 256), dim3(256), 0, stream>>>(x, xb);
    convert_xft<<<dim3((NN * 64 + 255) / 256), dim3(256), 0, stream>>>(x_ft, xftb);

    // 3. degree + CSR
    hipMemsetAsync(cnt, 0, (size_t)NN * 4, stream);
    count_deg<<<dim3((NE + 255) / 256), dim3(256), 0, stream>>>(e_dst, cnt);
    make_deginv<<<dim3((NN + 255) / 256), dim3(256), 0, stream>>>(cnt, deg_inv);
    scan_kernel<<<dim3(1), dim3(256), 0, stream>>>(cnt, ofs, cursor);
    fill_csr<<<dim3((NE + 255) / 256), dim3(256), 0, stream>>>(e_src, e_dst, deg_inv, cursor, csr_src, csr_cf);

    // 4. input MLPs (bf16 MFMA, bf16 out)
    mfma_gemm<128, true, true><<<dim3(3, 157), dim3(256), 0, stream>>>(
        xb, 736, Wt + O_CAT, bcat, nullptr, h0b, 384, NN, 736);
    mfma_gemm<128, true, true><<<dim3(3, 157), dim3(256), 0, stream>>>(
        xftb, 64, Wt + O_OM, bomc, nullptr, g0b, 384, NN, 64);

    // 5. three GCN layers. jkb = bf16 [h1 h2 h3 g1 g2 g3], stride 768
    mfma_gemm_dual<<<dim3(2, 157, 2), dim3(256), 0, stream>>>(
        h0b, g0b, 384, Wt + O_C0, Wt + O_O0, tmpAb, tmpBb, 128, NN, 384);
    aggregate_slices<<<dim3(4 * NN), dim3(256), 0, stream>>>(
        tmpAb, tmpBb, b_c[0], b_o[0], ofs, csr_src, csr_cf, deg_inv, jkb, 0, 384);

    mfma_gemm_dual<<<dim3(2, 157, 2), dim3(256), 0, stream>>>(
        jkb + 0, jkb + 384, 768, Wt + O_C1, Wt + O_O1, tmpAb, tmpBb, 128, NN, 128);
    aggregate_slices<<<dim3(4 * NN), dim3(256), 0, stream>>>(
        tmpAb, tmpBb, b_c[1], b_o[1], ofs, csr_src, csr_cf, deg_inv, jkb, 128, 512);

    mfma_gemm_dual<<<dim3(2, 157, 2), dim3(256), 0, stream>>>(
        jkb + 128, jkb + 512, 768, Wt + O_C2, Wt + O_O2, tmpAb, tmpBb, 128, NN, 128);
    aggregate_slices<<<dim3(4 * NN), dim3(256), 0, stream>>>(
        tmpAb, tmpBb, b_c[2], b_o[2], ofs, csr_src, csr_cf, deg_inv, jkb, 256, 640);

    // 6. latent: zb = act(jkb @ W_lat + b_lat), bf16
    mfma_gemm<128, true, true><<<dim3(3, 157), dim3(256), 0, stream>>>(
        jkb, 768, Wt + O_LAT, b_lat, nullptr, zb, 384, NN, 768);

    // 7. fused heads GEMM (M=256): tmpH = act(zb @ [Wd|Ws] + [bd|bs]), fp32
    mfma_gemm<128, true, false><<<dim3(2, 157), dim3(256), 0, stream>>>(
        zb, 384, Wt + O_HEADS, bheads, tmpH, nullptr, 256, NN, 384);
    heads_kernel<<<dim3((NN + 3) / 4), dim3(256), 0, stream>>>(
        tmpH, W_odrug, b_odrug, W_odis, b_odis, out);
}

// Round 4
// 563.294 us; speedup vs baseline: 1.9422x; 1.1983x over previous
//
#include <hip/hip_runtime.h>
#include <cstdint>

#define NN 20000
#define NNP 20096            // 157 * 128, padded row count for all activation buffers
#define NE 640000
#define NEG_SLOPE 0.1f

typedef unsigned short ushort_t;
typedef __attribute__((ext_vector_type(8))) short short8;
typedef __attribute__((ext_vector_type(4))) float f32x4;

__device__ __forceinline__ unsigned short f2bf(float f) {
    union { float f; unsigned u; } v; v.f = f;
    unsigned r = v.u + 0x7fffu + ((v.u >> 16) & 1u);
    return (unsigned short)(r >> 16);
}
__device__ __forceinline__ float bflo(unsigned u) { return __uint_as_float(u << 16); }
__device__ __forceinline__ float bfhi(unsigned u) { return __uint_as_float(u & 0xffff0000u); }

__device__ __forceinline__ int swz(int r) { return (r ^ (r >> 2)) & 3; }

__device__ __forceinline__ void gld_lds16(const void* g, void* l) {
    __builtin_amdgcn_global_load_lds(
        (const __attribute__((address_space(1))) void*)g,
        (__attribute__((address_space(3))) void*)l,
        16, 0, 0);
}

// ---------------- packed Wt region offsets (elements, bf16) ----------------
// All Wt stored as [M][K] row-major (transposed from source [K][M])
#define O_CAT   0            // 384 x 736
#define O_OM    282624       // 384 x 64 (K padded 54->64 with zeros)
#define O_C0    307200       // 128 x 384
#define O_O0    356352       // 128 x 384
#define O_C1    405504       // 128 x 128
#define O_O1    421888
#define O_C2    438272
#define O_O2    454656
#define O_LAT   471040       // 384 x 768
#define O_HEADS 765952       // 256 x 384  (rows 0..127 = drug, 128..255 = dis)
#define WT_TOTAL 864256

__global__ __launch_bounds__(256) void pack_weights(
    const float* __restrict__ Wpe, const float* __restrict__ Wgos, const float* __restrict__ Wprot,
    const float* __restrict__ bpe, const float* __restrict__ bgos, const float* __restrict__ bprot,
    const float* __restrict__ Wom0, const float* __restrict__ Wom1,
    const float* __restrict__ Wom2, const float* __restrict__ Wom3,
    const float* __restrict__ bom0, const float* __restrict__ bom1,
    const float* __restrict__ bom2, const float* __restrict__ bom3,
    const float* __restrict__ Wc0, const float* __restrict__ Wo0,
    const float* __restrict__ Wc1, const float* __restrict__ Wo1,
    const float* __restrict__ Wc2, const float* __restrict__ Wo2,
    const float* __restrict__ Wlat,
    const float* __restrict__ Wdrug, const float* __restrict__ Wdis,
    const float* __restrict__ bdrug, const float* __restrict__ bdis,
    ushort_t* __restrict__ Wt, float* __restrict__ bcat, float* __restrict__ bomc,
    float* __restrict__ bheads)
{
    int i = blockIdx.x * blockDim.x + threadIdx.x;
    if (i < 282624) {                            // WtCat 384 x 736
        int m = i / 736, k = i % 736;
        float v = (k < 128) ? Wpe[k * 384 + m]
                : (k < 256) ? Wgos[(k - 128) * 384 + m]
                            : Wprot[(k - 256) * 384 + m];
        Wt[O_CAT + i] = f2bf(v);
        return;
    }
    i -= 282624;
    if (i < 24576) {                             // WtOm 384 x 64
        int m = i / 64, k = i % 64;
        float v = (k < 3)  ? Wom0[k * 384 + m]
                : (k < 6)  ? Wom1[(k - 3) * 384 + m]
                : (k < 30) ? Wom2[(k - 6) * 384 + m]
                : (k < 54) ? Wom3[(k - 30) * 384 + m] : 0.f;
        Wt[O_OM + i] = f2bf(v);
        return;
    }
    i -= 24576;
    if (i < 49152) { int m = i / 384, k = i % 384; Wt[O_C0 + i] = f2bf(Wc0[k * 128 + m]); return; }
    i -= 49152;
    if (i < 49152) { int m = i / 384, k = i % 384; Wt[O_O0 + i] = f2bf(Wo0[k * 128 + m]); return; }
    i -= 49152;
    if (i < 16384) { int m = i / 128, k = i % 128; Wt[O_C1 + i] = f2bf(Wc1[k * 128 + m]); return; }
    i -= 16384;
    if (i < 16384) { int m = i / 128, k = i % 128; Wt[O_O1 + i] = f2bf(Wo1[k * 128 + m]); return; }
    i -= 16384;
    if (i < 16384) { int m = i / 128, k = i % 128; Wt[O_C2 + i] = f2bf(Wc2[k * 128 + m]); return; }
    i -= 16384;
    if (i < 16384) { int m = i / 128, k = i % 128; Wt[O_O2 + i] = f2bf(Wo2[k * 128 + m]); return; }
    i -= 16384;
    if (i < 294912) { int m = i / 768, k = i % 768; Wt[O_LAT + i] = f2bf(Wlat[k * 384 + m]); return; }
    i -= 294912;
    if (i < 98304) {                             // heads 256 x 384
        int m = i / 384, k = i % 384;
        float v = (m < 128) ? Wdrug[k * 128 + m] : Wdis[k * 128 + (m - 128)];
        Wt[O_HEADS + i] = f2bf(v);
        return;
    }
    i -= 98304;
    if (i < 384) { bcat[i] = bpe[i] + bgos[i] + bprot[i]; return; }
    i -= 384;
    if (i < 384) { bomc[i] = bom0[i] + bom1[i] + bom2[i] + bom3[i]; return; }
    i -= 384;
    if (i < 256) { bheads[i] = (i < 128) ? bdrug[i] : bdis[i - 128]; return; }
}

// ---------------- input conversions ----------------
__global__ __launch_bounds__(256) void convert_x(const float* __restrict__ x, ushort_t* __restrict__ xb)
{
    int i = blockIdx.x * blockDim.x + threadIdx.x;
    int base = i * 4;
    if (base >= NN * 736) return;
    float4 v = *reinterpret_cast<const float4*>(&x[base]);
    unsigned long long p = (unsigned long long)f2bf(v.x)
                         | ((unsigned long long)f2bf(v.y) << 16)
                         | ((unsigned long long)f2bf(v.z) << 32)
                         | ((unsigned long long)f2bf(v.w) << 48);
    *reinterpret_cast<unsigned long long*>(&xb[base]) = p;
}

__global__ __launch_bounds__(256) void convert_xft(const float* __restrict__ xft, ushort_t* __restrict__ xftb)
{
    int i = blockIdx.x * blockDim.x + threadIdx.x;
    if (i >= NN * 64) return;
    int r = i >> 6, c = i & 63;
    float v = (c < 54) ? xft[r * 54 + c] : 0.f;
    xftb[i] = f2bf(v);
}

// ---------------- degree / CSR ----------------
__global__ __launch_bounds__(256) void count_deg(const int* __restrict__ dst, int* __restrict__ cnt)
{
    int e = blockIdx.x * blockDim.x + threadIdx.x;
    if (e < NE) atomicAdd(&cnt[dst[e]], 1);
}

__global__ __launch_bounds__(256) void make_deginv(const int* __restrict__ cnt, float* __restrict__ deg_inv)
{
    int i = blockIdx.x * blockDim.x + threadIdx.x;
    if (i < NN) deg_inv[i] = rsqrtf((float)cnt[i] + 2.0f);
}

__global__ __launch_bounds__(256) void scan_kernel(const int* __restrict__ cnt,
                                                   int* __restrict__ ofs, int* __restrict__ cursor)
{
    __shared__ int part[256];
    const int t = threadIdx.x;
    const int CH = (NN + 255) / 256;
    int base = t * CH;
    int s = 0;
    for (int i = 0; i < CH; i++) { int idx = base + i; if (idx < NN) s += cnt[idx]; }
    part[t] = s;
    __syncthreads();
    for (int off = 1; off < 256; off <<= 1) {
        int v = (t >= off) ? part[t - off] : 0;
        __syncthreads();
        part[t] += v;
        __syncthreads();
    }
    int run = (t == 0) ? 0 : part[t - 1];
    for (int i = 0; i < CH; i++) {
        int idx = base + i;
        if (idx < NN) { ofs[idx] = run; cursor[idx] = run; run += cnt[idx]; }
    }
    if (t == 255) ofs[NN] = run;
}

__global__ __launch_bounds__(256) void fill_csr(const int* __restrict__ src, const int* __restrict__ dst,
                                                const float* __restrict__ deg_inv,
                                                int* __restrict__ cursor,
                                                int* __restrict__ csr_src, float* __restrict__ csr_cf)
{
    int e = blockIdx.x * blockDim.x + threadIdx.x;
    if (e >= NE) return;
    int s = src[e], d = dst[e];
    int p = atomicAdd(&cursor[d], 1);
    csr_src[p] = s;
    csr_cf[p] = deg_inv[s] * deg_inv[d];
}

// ---------------- bf16 MFMA GEMM body ----------------
// C[nrows x M] = [act]( A(bf16, nrows x K, lda) @ Wt(bf16, [M][K])^T [+ bias] )
// BM=128, BK=32, 256 threads = 4 waves 2x2. A buffers must have >= gridDim.y*128 rows.
template<int BN, bool BIASACT, bool OUT_BF16>
__device__ __forceinline__ void gemm_body(
    ushort_t* As, ushort_t* Bs,
    const ushort_t* __restrict__ A, int lda,
    const ushort_t* __restrict__ Wt,
    const float* __restrict__ bias,
    float* __restrict__ Cf, ushort_t* __restrict__ Cb, int ldc,
    int nrows, int K, int row0, int col0)
{
    constexpr int BK = 32;
    constexpr int NI = (BN == 128) ? 4 : 2;

    const int t = threadIdx.x;
    const int w = t >> 6, lane = t & 63;
    const int wr = w >> 1, wc = w & 1;
    const int m16 = lane & 15, quad = lane >> 4;
    const int sr = lane >> 2;       // row within a 16-row staging chunk
    const int pgrp = lane & 3;      // physical 16B group within row

    f32x4 acc[4][NI];
#pragma unroll
    for (int mi = 0; mi < 4; mi++)
#pragma unroll
        for (int ni = 0; ni < NI; ni++) acc[mi][ni] = (f32x4)0.f;

    for (int k0 = 0; k0 < K; k0 += BK) {
#pragma unroll
        for (int p = 0; p < 2; p++) {
            int c = p * 4 + w;
            int r = c * 16 + sr;
            int q = pgrp ^ swz(r);
            gld_lds16(&A[(size_t)(row0 + r) * lda + k0 + q * 8], &As[c * 512]);
        }
#pragma unroll
        for (int p = 0; p < BN / 64; p++) {
            int c = p * 4 + w;
            int r = c * 16 + sr;
            int q = pgrp ^ swz(r);
            gld_lds16(&Wt[(size_t)(col0 + r) * K + k0 + q * 8], &Bs[c * 512]);
        }
        __syncthreads();

        short8 af[4], bfr[NI];
#pragma unroll
        for (int mi = 0; mi < 4; mi++) {
            int r = wr * 64 + mi * 16 + m16;
            int p = quad ^ swz(r);
            af[mi] = *reinterpret_cast<const short8*>(&As[r * 32 + p * 8]);
        }
#pragma unroll
        for (int ni = 0; ni < NI; ni++) {
            int n = wc * (NI * 16) + ni * 16 + m16;
            int p = quad ^ swz(n);
            bfr[ni] = *reinterpret_cast<const short8*>(&Bs[n * 32 + p * 8]);
        }
#pragma unroll
        for (int mi = 0; mi < 4; mi++)
#pragma unroll
            for (int ni = 0; ni < NI; ni++)
                acc[mi][ni] = __builtin_amdgcn_mfma_f32_16x16x32_bf16(af[mi], bfr[ni], acc[mi][ni], 0, 0, 0);
        __syncthreads();
    }

    // epilogue: C/D layout col=lane&15, row=quad*4+reg
#pragma unroll
    for (int mi = 0; mi < 4; mi++) {
#pragma unroll
        for (int reg = 0; reg < 4; reg++) {
            int grow = row0 + wr * 64 + mi * 16 + quad * 4 + reg;
            if (grow >= nrows) continue;
#pragma unroll
            for (int ni = 0; ni < NI; ni++) {
                int gcol = col0 + wc * (NI * 16) + ni * 16 + m16;
                float v = acc[mi][ni][reg];
                if constexpr (BIASACT) {
                    v += bias[gcol];
                    v = (v > 0.f) ? v : NEG_SLOPE * v;
                }
                if constexpr (OUT_BF16) Cb[(size_t)grow * ldc + gcol] = f2bf(v);
                else                    Cf[(size_t)grow * ldc + gcol] = v;
            }
        }
    }
}

template<int BN, bool BIASACT, bool OUT_BF16>
__global__ __launch_bounds__(256) void mfma_gemm(
    const ushort_t* __restrict__ A, int lda,
    const ushort_t* __restrict__ Wt,
    const float* __restrict__ bias,
    float* __restrict__ Cf, ushort_t* __restrict__ Cb, int ldc,
    int nrows, int K)
{
    __shared__ ushort_t As[128 * 32];
    __shared__ ushort_t Bs[BN * 32];
    gemm_body<BN, BIASACT, OUT_BF16>(As, Bs, A, lda, Wt, bias, Cf, Cb, ldc, nrows, K,
                                     blockIdx.y * 128, blockIdx.x * BN);
}

// z-batched dual GEMM (both GCN chains in one launch), BN=64, no bias, bf16 out
__global__ __launch_bounds__(256) void mfma_gemm_dual(
    const ushort_t* __restrict__ A0, const ushort_t* __restrict__ A1, int lda,
    const ushort_t* __restrict__ W0, const ushort_t* __restrict__ W1,
    ushort_t* __restrict__ C0, ushort_t* __restrict__ C1, int ldc,
    int nrows, int K)
{
    __shared__ ushort_t As[128 * 32];
    __shared__ ushort_t Bs[64 * 32];
    const ushort_t* A  = blockIdx.z ? A1 : A0;
    const ushort_t* Wt = blockIdx.z ? W1 : W0;
    ushort_t*       Cb = blockIdx.z ? C1 : C0;
    gemm_body<64, false, true>(As, Bs, A, lda, Wt, nullptr, nullptr, Cb, ldc, nrows, K,
                               blockIdx.y * 128, blockIdx.x * 64);
}

// ---------------- GCN aggregation: wave per (node, chain, half) ----------------
// 80000 waves, slice-major (slice = chain*2+half) so concurrent waves gather
// from the same 2.56 MB L2-resident table slice. Lane = 32 feature-pairs x 2
// edge-sublanes; register accumulation, single shfl_xor combine, no block
// barriers, no LDS reduction.
__global__ __launch_bounds__(256) void aggregate_wave(
    const ushort_t* __restrict__ tabA, const ushort_t* __restrict__ tabB,
    const float* __restrict__ bc, const float* __restrict__ bo,
    const int* __restrict__ ofs, const int* __restrict__ csr_src,
    const float* __restrict__ csr_cf, const float* __restrict__ deg_inv,
    ushort_t* __restrict__ outb, int hcol, int gcol)
{
    __shared__ int s_src[4][64];
    __shared__ float s_cf[4][64];
    const int w = threadIdx.x >> 6, lane = threadIdx.x & 63;
    const int task = blockIdx.x * 4 + w;
    const int slice = task / NN;                 // 0..3 = (chain<<1)|half
    const int i = task - slice * NN;
    const int chain = slice >> 1, half = slice & 1;
    const ushort_t* __restrict__ tab = chain ? tabB : tabA;
    const float* __restrict__ bias = chain ? bo : bc;
    const int el = lane >> 5;                    // edge sublane 0/1
    const int fl = lane & 31;                    // feature-pair index
    const int coloff = half * 64 + fl * 2;

    const int start = ofs[i], end = ofs[i + 1];
    float a0 = 0.f, a1 = 0.f;

    for (int base = start; base < end; base += 64) {
        int n = end - base; if (n > 64) n = 64;
        if (lane < n) {
            s_src[w][lane] = csr_src[base + lane];
            s_cf[w][lane]  = csr_cf[base + lane];
        }
        // wave-synchronous: LDS ops from one wave are in-order; no barrier needed
        int j = el;
        for (; j + 6 < n; j += 8) {
            int sa = s_src[w][j],     sb = s_src[w][j + 2];
            int sc = s_src[w][j + 4], sd = s_src[w][j + 6];
            float ca = s_cf[w][j],     cb = s_cf[w][j + 2];
            float cc = s_cf[w][j + 4], cd = s_cf[w][j + 6];
            unsigned pa = *reinterpret_cast<const unsigned*>(&tab[(size_t)sa * 128 + coloff]);
            unsigned pb = *reinterpret_cast<const unsigned*>(&tab[(size_t)sb * 128 + coloff]);
            unsigned pc = *reinterpret_cast<const unsigned*>(&tab[(size_t)sc * 128 + coloff]);
            unsigned pd = *reinterpret_cast<const unsigned*>(&tab[(size_t)sd * 128 + coloff]);
            a0 = fmaf(bflo(pa), ca, a0); a1 = fmaf(bfhi(pa), ca, a1);
            a0 = fmaf(bflo(pb), cb, a0); a1 = fmaf(bfhi(pb), cb, a1);
            a0 = fmaf(bflo(pc), cc, a0); a1 = fmaf(bfhi(pc), cc, a1);
            a0 = fmaf(bflo(pd), cd, a0); a1 = fmaf(bfhi(pd), cd, a1);
        }
        for (; j < n; j += 2) {
            int s = s_src[w][j];
            float cf = s_cf[w][j];
            unsigned pv = *reinterpret_cast<const unsigned*>(&tab[(size_t)s * 128 + coloff]);
            a0 = fmaf(bflo(pv), cf, a0);
            a1 = fmaf(bfhi(pv), cf, a1);
        }
    }
    a0 += __shfl_xor(a0, 32);
    a1 += __shfl_xor(a1, 32);
    if (el == 0) {
        float di = deg_inv[i];
        float c = 2.f * di * di;
        unsigned pv = *reinterpret_cast<const unsigned*>(&tab[(size_t)i * 128 + coloff]);
        a0 = fmaf(bflo(pv), c, a0);
        a1 = fmaf(bfhi(pv), c, a1);
        a0 += bias[coloff];
        a1 += bias[coloff + 1];
        a0 = (a0 > 0.f) ? a0 : NEG_SLOPE * a0;
        a1 = (a1 > 0.f) ? a1 : NEG_SLOPE * a1;
        int col = (chain ? gcol : hcol) + coloff;
        unsigned o = (unsigned)f2bf(a0) | ((unsigned)f2bf(a1) << 16);
        *reinterpret_cast<unsigned*>(&outb[(size_t)i * 768 + col]) = o;
    }
}

// ---------------- final 2-wide heads: wave per node ----------------
__global__ __launch_bounds__(256) void heads_kernel(
    const float* __restrict__ tmpH,
    const float* __restrict__ Wod, const float* __restrict__ bod,
    const float* __restrict__ Wos, const float* __restrict__ bos,
    float* __restrict__ out)
{
    int w = threadIdx.x >> 6, lane = threadIdx.x & 63;
    int i = blockIdx.x * 4 + w;
    if (i >= NN) return;
    float a0 = 0.f, a1 = 0.f, d0 = 0.f, d1 = 0.f;
#pragma unroll
    for (int p = 0; p < 2; p++) {
        int k = lane + p * 64;
        float vd = tmpH[(size_t)i * 256 + k];
        float vs = tmpH[(size_t)i * 256 + 128 + k];
        a0 = fmaf(vd, Wod[k * 2 + 0], a0);
        a1 = fmaf(vd, Wod[k * 2 + 1], a1);
        d0 = fmaf(vs, Wos[k * 2 + 0], d0);
        d1 = fmaf(vs, Wos[k * 2 + 1], d1);
    }
    for (int off = 32; off; off >>= 1) {
        a0 += __shfl_down(a0, off);
        a1 += __shfl_down(a1, off);
        d0 += __shfl_down(d0, off);
        d1 += __shfl_down(d1, off);
    }
    if (lane == 0) {
        out[(size_t)i * 4 + 0] = a0 + bod[0];
        out[(size_t)i * 4 + 1] = a1 + bod[1];
        out[(size_t)i * 4 + 2] = d0 + bos[0];
        out[(size_t)i * 4 + 3] = d1 + bos[1];
    }
}

// ---------------- launch ----------------
extern "C" void kernel_launch(void* const* d_in, const int* in_sizes, int n_in,
                              void* d_out, int out_size, void* d_ws, size_t ws_size,
                              hipStream_t stream)
{
    const float* x      = (const float*)d_in[0];
    const float* x_ft   = (const float*)d_in[1];
    const int*   eidx   = (const int*)d_in[2];
    const float* W_pe   = (const float*)d_in[3];
    const float* b_pe   = (const float*)d_in[4];
    const float* W_gos  = (const float*)d_in[5];
    const float* b_gos  = (const float*)d_in[6];
    const float* W_prot = (const float*)d_in[7];
    const float* b_prot = (const float*)d_in[8];
    const float* W_om0  = (const float*)d_in[9];
    const float* b_om0  = (const float*)d_in[10];
    const float* W_om1  = (const float*)d_in[11];
    const float* b_om1  = (const float*)d_in[12];
    const float* W_om2  = (const float*)d_in[13];
    const float* b_om2  = (const float*)d_in[14];
    const float* W_om3  = (const float*)d_in[15];
    const float* b_om3  = (const float*)d_in[16];
    const float* W_c[3] = {(const float*)d_in[17], (const float*)d_in[21], (const float*)d_in[25]};
    const float* b_c[3] = {(const float*)d_in[18], (const float*)d_in[22], (const float*)d_in[26]};
    const float* W_o[3] = {(const float*)d_in[19], (const float*)d_in[23], (const float*)d_in[27]};
    const float* b_o[3] = {(const float*)d_in[20], (const float*)d_in[24], (const float*)d_in[28]};
    const float* W_lat  = (const float*)d_in[29];
    const float* b_lat  = (const float*)d_in[30];
    const float* W_drug = (const float*)d_in[31];
    const float* b_drug = (const float*)d_in[32];
    const float* W_dis  = (const float*)d_in[33];
    const float* b_dis  = (const float*)d_in[34];
    const float* W_odrug= (const float*)d_in[35];
    const float* b_odrug= (const float*)d_in[36];
    const float* W_odis = (const float*)d_in[37];
    const float* b_odis = (const float*)d_in[38];
    float* out = (float*)d_out;

    const int* e_src = eidx;
    const int* e_dst = eidx + NE;

    char* p = (char*)d_ws;
    auto alloc = [&](size_t bytes) -> void* {
        void* r = (void*)p;
        p += (bytes + 255) & ~(size_t)255;
        return r;
    };
    ushort_t* Wt    = (ushort_t*)alloc((size_t)WT_TOTAL * 2);
    float* bcat     = (float*)alloc(384 * 4);
    float* bomc     = (float*)alloc(384 * 4);
    float* bheads   = (float*)alloc(256 * 4);
    float* deg_inv  = (float*)alloc((size_t)NN * 4);
    int*   cnt      = (int*)alloc((size_t)NN * 4);
    int*   ofs      = (int*)alloc((size_t)(NN + 1) * 4);
    int*   cursor   = (int*)alloc((size_t)NN * 4);
    int*   csr_src  = (int*)alloc((size_t)NE * 4);
    float* csr_cf   = (float*)alloc((size_t)NE * 4);
    ushort_t* xb    = (ushort_t*)alloc((size_t)NNP * 736 * 2);
    ushort_t* xftb  = (ushort_t*)alloc((size_t)NNP * 64 * 2);
    ushort_t* h0b   = (ushort_t*)alloc((size_t)NNP * 384 * 2);
    ushort_t* g0b   = (ushort_t*)alloc((size_t)NNP * 384 * 2);
    ushort_t* jkb   = (ushort_t*)alloc((size_t)NNP * 768 * 2);
    ushort_t* zb    = (ushort_t*)alloc((size_t)NNP * 384 * 2);
    ushort_t* tmpAb = (ushort_t*)alloc((size_t)NNP * 128 * 2);
    ushort_t* tmpBb = (ushort_t*)alloc((size_t)NNP * 128 * 2);
    float* tmpH     = (float*)alloc((size_t)NNP * 256 * 4);
    (void)ws_size; (void)in_sizes; (void)n_in; (void)out_size;

    // 1. pack + transpose weights to bf16 [M][K]
    {
        int total = WT_TOTAL + 384 + 384 + 256;
        pack_weights<<<dim3((total + 255) / 256), dim3(256), 0, stream>>>(
            W_pe, W_gos, W_prot, b_pe, b_gos, b_prot,
            W_om0, W_om1, W_om2, W_om3, b_om0, b_om1, b_om2, b_om3,
            W_c[0], W_o[0], W_c[1], W_o[1], W_c[2], W_o[2],
            W_lat, W_drug, W_dis, b_drug, b_dis, Wt, bcat, bomc, bheads);
    }
    // 2. convert inputs to bf16
    convert_x<<<dim3((NN * 736 / 4 + 255) / 256), dim3(256), 0, stream>>>(x, xb);
    convert_xft<<<dim3((NN * 64 + 255) / 256), dim3(256), 0, stream>>>(x_ft, xftb);

    // 3. degree + CSR
    hipMemsetAsync(cnt, 0, (size_t)NN * 4, stream);
    count_deg<<<dim3((NE + 255) / 256), dim3(256), 0, stream>>>(e_dst, cnt);
    make_deginv<<<dim3((NN + 255) / 256), dim3(256), 0, stream>>>(cnt, deg_inv);
    scan_kernel<<<dim3(1), dim3(256), 0, stream>>>(cnt, ofs, cursor);
    fill_csr<<<dim3((NE + 255) / 256), dim3(256), 0, stream>>>(e_src, e_dst, deg_inv, cursor, csr_src, csr_cf);

    // 4. input MLPs (bf16 MFMA, bf16 out)
    mfma_gemm<128, true, true><<<dim3(3, 157), dim3(256), 0, stream>>>(
        xb, 736, Wt + O_CAT, bcat, nullptr, h0b, 384, NN, 736);
    mfma_gemm<128, true, true><<<dim3(3, 157), dim3(256), 0, stream>>>(
        xftb, 64, Wt + O_OM, bomc, nullptr, g0b, 384, NN, 64);

    // 5. three GCN layers. jkb = bf16 [h1 h2 h3 g1 g2 g3], stride 768
    mfma_gemm_dual<<<dim3(2, 157, 2), dim3(256), 0, stream>>>(
        h0b, g0b, 384, Wt + O_C0, Wt + O_O0, tmpAb, tmpBb, 128, NN, 384);
    aggregate_wave<<<dim3(NN), dim3(256), 0, stream>>>(
        tmpAb, tmpBb, b_c[0], b_o[0], ofs, csr_src, csr_cf, deg_inv, jkb, 0, 384);

    mfma_gemm_dual<<<dim3(2, 157, 2), dim3(256), 0, stream>>>(
        jkb + 0, jkb + 384, 768, Wt + O_C1, Wt + O_O1, tmpAb, tmpBb, 128, NN, 128);
    aggregate_wave<<<dim3(NN), dim3(256), 0, stream>>>(
        tmpAb, tmpBb, b_c[1], b_o[1], ofs, csr_src, csr_cf, deg_inv, jkb, 128, 512);

    mfma_gemm_dual<<<dim3(2, 157, 2), dim3(256), 0, stream>>>(
        jkb + 128, jkb + 512, 768, Wt + O_C2, Wt + O_O2, tmpAb, tmpBb, 128, NN, 128);
    aggregate_wave<<<dim3(NN), dim3(256), 0, stream>>>(
        tmpAb, tmpBb, b_c[2], b_o[2], ofs, csr_src, csr_cf, deg_inv, jkb, 256, 640);

    // 6. latent: zb = act(jkb @ W_lat + b_lat), bf16
    mfma_gemm<128, true, true><<<dim3(3, 157), dim3(256), 0, stream>>>(
        jkb, 768, Wt + O_LAT, b_lat, nullptr, zb, 384, NN, 768);

    // 7. fused heads GEMM (M=256): tmpH = act(zb @ [Wd|Ws] + [bd|bs]), fp32
    mfma_gemm<128, true, false><<<dim3(2, 157), dim3(256), 0, stream>>>(
        zb, 384, Wt + O_HEADS, bheads, tmpH, nullptr, 256, NN, 384);
    heads_kernel<<<dim3((NN + 3) / 4), dim3(256), 0, stream>>>(
        tmpH, W_odrug, b_odrug, W_odis, b_odis, out);
}

// Round 5
// 508.879 us; speedup vs baseline: 2.1499x; 1.1069x over previous
//
#include <hip/hip_runtime.h>
#include <cstdint>

#define NN 20000
#define NNP 20096            // 157 * 128, padded row count for all activation buffers
#define NE 640000
#define NEG_SLOPE 0.1f
#define NSCAN 79             // ceil(NN/256)
#define NSL 8                // dst slices (XCD-count)
#define NPSL 2500            // nodes per slice
#define FBPS 160             // fill blocks per slice

typedef unsigned short ushort_t;
typedef __attribute__((ext_vector_type(8))) short short8;
typedef __attribute__((ext_vector_type(4))) float f32x4;

__device__ __forceinline__ unsigned short f2bf(float f) {
    union { float f; unsigned u; } v; v.f = f;
    unsigned r = v.u + 0x7fffu + ((v.u >> 16) & 1u);
    return (unsigned short)(r >> 16);
}
__device__ __forceinline__ float bflo(unsigned u) { return __uint_as_float(u << 16); }
__device__ __forceinline__ float bfhi(unsigned u) { return __uint_as_float(u & 0xffff0000u); }

__device__ __forceinline__ int swz(int r) { return (r ^ (r >> 2)) & 3; }

__device__ __forceinline__ void gld_lds16(const void* g, void* l) {
    __builtin_amdgcn_global_load_lds(
        (const __attribute__((address_space(1))) void*)g,
        (__attribute__((address_space(3))) void*)l,
        16, 0, 0);
}

// ---------------- packed Wt region offsets (elements, bf16) ----------------
// All Wt stored as [M][K] row-major (transposed from source [K][M])
#define O_CAT   0            // 384 x 736
#define O_OM    282624       // 384 x 64 (K padded 54->64 with zeros)
#define O_C0    307200       // 128 x 384
#define O_O0    356352       // 128 x 384
#define O_C1    405504       // 128 x 128
#define O_O1    421888
#define O_C2    438272
#define O_O2    454656
#define O_LAT   471040       // 384 x 768
#define O_HEADS 765952       // 256 x 384  (rows 0..127 = drug, 128..255 = dis)
#define WT_TOTAL 864256

__global__ __launch_bounds__(256) void pack_weights(
    const float* __restrict__ Wpe, const float* __restrict__ Wgos, const float* __restrict__ Wprot,
    const float* __restrict__ bpe, const float* __restrict__ bgos, const float* __restrict__ bprot,
    const float* __restrict__ Wom0, const float* __restrict__ Wom1,
    const float* __restrict__ Wom2, const float* __restrict__ Wom3,
    const float* __restrict__ bom0, const float* __restrict__ bom1,
    const float* __restrict__ bom2, const float* __restrict__ bom3,
    const float* __restrict__ Wc0, const float* __restrict__ Wo0,
    const float* __restrict__ Wc1, const float* __restrict__ Wo1,
    const float* __restrict__ Wc2, const float* __restrict__ Wo2,
    const float* __restrict__ Wlat,
    const float* __restrict__ Wdrug, const float* __restrict__ Wdis,
    const float* __restrict__ bdrug, const float* __restrict__ bdis,
    ushort_t* __restrict__ Wt, float* __restrict__ bcat, float* __restrict__ bomc,
    float* __restrict__ bheads)
{
    int i = blockIdx.x * blockDim.x + threadIdx.x;
    if (i < 282624) {                            // WtCat 384 x 736
        int m = i / 736, k = i % 736;
        float v = (k < 128) ? Wpe[k * 384 + m]
                : (k < 256) ? Wgos[(k - 128) * 384 + m]
                            : Wprot[(k - 256) * 384 + m];
        Wt[O_CAT + i] = f2bf(v);
        return;
    }
    i -= 282624;
    if (i < 24576) {                             // WtOm 384 x 64
        int m = i / 64, k = i % 64;
        float v = (k < 3)  ? Wom0[k * 384 + m]
                : (k < 6)  ? Wom1[(k - 3) * 384 + m]
                : (k < 30) ? Wom2[(k - 6) * 384 + m]
                : (k < 54) ? Wom3[(k - 30) * 384 + m] : 0.f;
        Wt[O_OM + i] = f2bf(v);
        return;
    }
    i -= 24576;
    if (i < 49152) { int m = i / 384, k = i % 384; Wt[O_C0 + i] = f2bf(Wc0[k * 128 + m]); return; }
    i -= 49152;
    if (i < 49152) { int m = i / 384, k = i % 384; Wt[O_O0 + i] = f2bf(Wo0[k * 128 + m]); return; }
    i -= 49152;
    if (i < 16384) { int m = i / 128, k = i % 128; Wt[O_C1 + i] = f2bf(Wc1[k * 128 + m]); return; }
    i -= 16384;
    if (i < 16384) { int m = i / 128, k = i % 128; Wt[O_O1 + i] = f2bf(Wo1[k * 128 + m]); return; }
    i -= 16384;
    if (i < 16384) { int m = i / 128, k = i % 128; Wt[O_C2 + i] = f2bf(Wc2[k * 128 + m]); return; }
    i -= 16384;
    if (i < 16384) { int m = i / 128, k = i % 128; Wt[O_O2 + i] = f2bf(Wo2[k * 128 + m]); return; }
    i -= 16384;
    if (i < 294912) { int m = i / 768, k = i % 768; Wt[O_LAT + i] = f2bf(Wlat[k * 384 + m]); return; }
    i -= 294912;
    if (i < 98304) {                             // heads 256 x 384
        int m = i / 384, k = i % 384;
        float v = (m < 128) ? Wdrug[k * 128 + m] : Wdis[k * 128 + (m - 128)];
        Wt[O_HEADS + i] = f2bf(v);
        return;
    }
    i -= 98304;
    if (i < 384) { bcat[i] = bpe[i] + bgos[i] + bprot[i]; return; }
    i -= 384;
    if (i < 384) { bomc[i] = bom0[i] + bom1[i] + bom2[i] + bom3[i]; return; }
    i -= 384;
    if (i < 256) { bheads[i] = (i < 128) ? bdrug[i] : bdis[i - 128]; return; }
}

// ---------------- input conversions ----------------
__global__ __launch_bounds__(256) void convert_x(const float* __restrict__ x, ushort_t* __restrict__ xb)
{
    int i = blockIdx.x * blockDim.x + threadIdx.x;
    int base = i * 4;
    if (base >= NN * 736) return;
    float4 v = *reinterpret_cast<const float4*>(&x[base]);
    unsigned long long p = (unsigned long long)f2bf(v.x)
                         | ((unsigned long long)f2bf(v.y) << 16)
                         | ((unsigned long long)f2bf(v.z) << 32)
                         | ((unsigned long long)f2bf(v.w) << 48);
    *reinterpret_cast<unsigned long long*>(&xb[base]) = p;
}

__global__ __launch_bounds__(256) void convert_xft(const float* __restrict__ xft, ushort_t* __restrict__ xftb)
{
    int i = blockIdx.x * blockDim.x + threadIdx.x;
    if (i >= NN * 64) return;
    int r = i >> 6, c = i & 63;
    float v = (c < 54) ? xft[r * 54 + c] : 0.f;
    xftb[i] = f2bf(v);
}

// ---------------- degree / CSR (sliced: slice = blockIdx.x & 7 owns 2500 dsts) ----
__global__ __launch_bounds__(256) void count_deg_sliced(const int* __restrict__ dst, int* __restrict__ cnt)
{
    const int slice = blockIdx.x & (NSL - 1);
    const int blk = blockIdx.x >> 3;
    const int lo = slice * NPSL, hi = lo + NPSL;
    for (int e = blk * 256 + threadIdx.x; e < NE; e += FBPS * 256) {
        int d = dst[e];
        if (d >= lo && d < hi) atomicAdd(&cnt[d], 1);
    }
}

__global__ __launch_bounds__(256) void make_deginv(const int* __restrict__ cnt, float* __restrict__ deg_inv)
{
    int i = blockIdx.x * blockDim.x + threadIdx.x;
    if (i < NN) deg_inv[i] = rsqrtf((float)cnt[i] + 2.0f);
}

// hierarchical scan: per-block sums -> tiny top scan -> apply
__global__ __launch_bounds__(256) void scan_blocksums(const int* __restrict__ cnt, int* __restrict__ bsum)
{
    __shared__ int s[256];
    int t = threadIdx.x, i = blockIdx.x * 256 + t;
    s[t] = (i < NN) ? cnt[i] : 0;
    __syncthreads();
    for (int off = 128; off; off >>= 1) {
        if (t < off) s[t] += s[t + off];
        __syncthreads();
    }
    if (t == 0) bsum[blockIdx.x] = s[0];
}

__global__ __launch_bounds__(128) void scan_tops(const int* __restrict__ bsum,
                                                 int* __restrict__ boff, int* __restrict__ ofs)
{
    __shared__ int s[NSCAN];
    int t = threadIdx.x;
    if (t < NSCAN) s[t] = bsum[t];
    __syncthreads();
    if (t == 0) {
        int run = 0;
        for (int b = 0; b < NSCAN; b++) { int x = s[b]; s[b] = run; run += x; }
        ofs[NN] = run;
    }
    __syncthreads();
    if (t < NSCAN) boff[t] = s[t];
}

__global__ __launch_bounds__(256) void scan_apply(const int* __restrict__ cnt, const int* __restrict__ boff,
                                                  int* __restrict__ ofs, int* __restrict__ cursor)
{
    __shared__ int s[256];
    int t = threadIdx.x, i = blockIdx.x * 256 + t;
    int v = (i < NN) ? cnt[i] : 0;
    s[t] = v;
    __syncthreads();
    for (int off = 1; off < 256; off <<= 1) {
        int u = (t >= off) ? s[t - off] : 0;
        __syncthreads();
        s[t] += u;
        __syncthreads();
    }
    int excl = s[t] - v + boff[blockIdx.x];
    if (i < NN) { ofs[i] = excl; cursor[i] = excl; }
}

// sliced fill: per-slice cursor atomics hit a 10 KB region; csr writes land in a
// contiguous ~640 KB per-slice region; packed (src, cf) = one 8 B write per edge.
__global__ __launch_bounds__(256) void fill_csr_sliced(
    const int* __restrict__ src, const int* __restrict__ dst,
    const float* __restrict__ deg_inv, int* __restrict__ cursor,
    uint2* __restrict__ csr_pk)
{
    const int slice = blockIdx.x & (NSL - 1);
    const int blk = blockIdx.x >> 3;
    const int lo = slice * NPSL, hi = lo + NPSL;
    for (int e = blk * 256 + threadIdx.x; e < NE; e += FBPS * 256) {
        int d = dst[e];
        if (d >= lo && d < hi) {
            int s = src[e];
            int p = atomicAdd(&cursor[d], 1);
            float cf = deg_inv[s] * deg_inv[d];
            csr_pk[p] = make_uint2((unsigned)s, __float_as_uint(cf));
        }
    }
}

// ---------------- bf16 MFMA GEMM body ----------------
// C[nrows x M] = [act]( A(bf16, nrows x K, lda) @ Wt(bf16, [M][K])^T [+ bias] )
// BM=128, BK=32, 256 threads = 4 waves 2x2. A buffers must have >= gridDim.y*128 rows.
template<int BN, bool BIASACT, bool OUT_BF16>
__device__ __forceinline__ void gemm_body(
    ushort_t* As, ushort_t* Bs,
    const ushort_t* __restrict__ A, int lda,
    const ushort_t* __restrict__ Wt,
    const float* __restrict__ bias,
    float* __restrict__ Cf, ushort_t* __restrict__ Cb, int ldc,
    int nrows, int K, int row0, int col0)
{
    constexpr int BK = 32;
    constexpr int NI = (BN == 128) ? 4 : 2;

    const int t = threadIdx.x;
    const int w = t >> 6, lane = t & 63;
    const int wr = w >> 1, wc = w & 1;
    const int m16 = lane & 15, quad = lane >> 4;
    const int sr = lane >> 2;       // row within a 16-row staging chunk
    const int pgrp = lane & 3;      // physical 16B group within row

    f32x4 acc[4][NI];
#pragma unroll
    for (int mi = 0; mi < 4; mi++)
#pragma unroll
        for (int ni = 0; ni < NI; ni++) acc[mi][ni] = (f32x4)0.f;

    for (int k0 = 0; k0 < K; k0 += BK) {
#pragma unroll
        for (int p = 0; p < 2; p++) {
            int c = p * 4 + w;
            int r = c * 16 + sr;
            int q = pgrp ^ swz(r);
            gld_lds16(&A[(size_t)(row0 + r) * lda + k0 + q * 8], &As[c * 512]);
        }
#pragma unroll
        for (int p = 0; p < BN / 64; p++) {
            int c = p * 4 + w;
            int r = c * 16 + sr;
            int q = pgrp ^ swz(r);
            gld_lds16(&Wt[(size_t)(col0 + r) * K + k0 + q * 8], &Bs[c * 512]);
        }
        __syncthreads();

        short8 af[4], bfr[NI];
#pragma unroll
        for (int mi = 0; mi < 4; mi++) {
            int r = wr * 64 + mi * 16 + m16;
            int p = quad ^ swz(r);
            af[mi] = *reinterpret_cast<const short8*>(&As[r * 32 + p * 8]);
        }
#pragma unroll
        for (int ni = 0; ni < NI; ni++) {
            int n = wc * (NI * 16) + ni * 16 + m16;
            int p = quad ^ swz(n);
            bfr[ni] = *reinterpret_cast<const short8*>(&Bs[n * 32 + p * 8]);
        }
#pragma unroll
        for (int mi = 0; mi < 4; mi++)
#pragma unroll
            for (int ni = 0; ni < NI; ni++)
                acc[mi][ni] = __builtin_amdgcn_mfma_f32_16x16x32_bf16(af[mi], bfr[ni], acc[mi][ni], 0, 0, 0);
        __syncthreads();
    }

    // epilogue: C/D layout col=lane&15, row=quad*4+reg
#pragma unroll
    for (int mi = 0; mi < 4; mi++) {
#pragma unroll
        for (int reg = 0; reg < 4; reg++) {
            int grow = row0 + wr * 64 + mi * 16 + quad * 4 + reg;
            if (grow >= nrows) continue;
#pragma unroll
            for (int ni = 0; ni < NI; ni++) {
                int gcol = col0 + wc * (NI * 16) + ni * 16 + m16;
                float v = acc[mi][ni][reg];
                if constexpr (BIASACT) {
                    v += bias[gcol];
                    v = (v > 0.f) ? v : NEG_SLOPE * v;
                }
                if constexpr (OUT_BF16) Cb[(size_t)grow * ldc + gcol] = f2bf(v);
                else                    Cf[(size_t)grow * ldc + gcol] = v;
            }
        }
    }
}

template<int BN, bool BIASACT, bool OUT_BF16>
__global__ __launch_bounds__(256) void mfma_gemm(
    const ushort_t* __restrict__ A, int lda,
    const ushort_t* __restrict__ Wt,
    const float* __restrict__ bias,
    float* __restrict__ Cf, ushort_t* __restrict__ Cb, int ldc,
    int nrows, int K)
{
    __shared__ ushort_t As[128 * 32];
    __shared__ ushort_t Bs[BN * 32];
    gemm_body<BN, BIASACT, OUT_BF16>(As, Bs, A, lda, Wt, bias, Cf, Cb, ldc, nrows, K,
                                     blockIdx.y * 128, blockIdx.x * BN);
}

// z-batched dual GEMM (both GCN chains in one launch), BN=64, no bias, bf16 out
__global__ __launch_bounds__(256) void mfma_gemm_dual(
    const ushort_t* __restrict__ A0, const ushort_t* __restrict__ A1, int lda,
    const ushort_t* __restrict__ W0, const ushort_t* __restrict__ W1,
    ushort_t* __restrict__ C0, ushort_t* __restrict__ C1, int ldc,
    int nrows, int K)
{
    __shared__ ushort_t As[128 * 32];
    __shared__ ushort_t Bs[64 * 32];
    const ushort_t* A  = blockIdx.z ? A1 : A0;
    const ushort_t* Wt = blockIdx.z ? W1 : W0;
    ushort_t*       Cb = blockIdx.z ? C1 : C0;
    gemm_body<64, false, true>(As, Bs, A, lda, Wt, nullptr, nullptr, Cb, ldc, nrows, K,
                               blockIdx.y * 128, blockIdx.x * 64);
}

// ---------------- GCN aggregation: wave per (node, chain, half) ----------------
// 80000 waves, slice-major (slice = chain*2+half) so concurrent waves gather
// from the same 2.56 MB L2-resident table slice. Lane = 32 feature-pairs x 2
// edge-sublanes; register accumulation, single shfl_xor combine, no block
// barriers, no LDS reduction. csr is packed uint2 (src, cf-bits).
__global__ __launch_bounds__(256) void aggregate_wave(
    const ushort_t* __restrict__ tabA, const ushort_t* __restrict__ tabB,
    const float* __restrict__ bc, const float* __restrict__ bo,
    const int* __restrict__ ofs, const uint2* __restrict__ csr_pk,
    const float* __restrict__ deg_inv,
    ushort_t* __restrict__ outb, int hcol, int gcol)
{
    __shared__ uint2 s_pk[4][64];
    const int w = threadIdx.x >> 6, lane = threadIdx.x & 63;
    const int task = blockIdx.x * 4 + w;
    const int slice = task / NN;                 // 0..3 = (chain<<1)|half
    const int i = task - slice * NN;
    const int chain = slice >> 1, half = slice & 1;
    const ushort_t* __restrict__ tab = chain ? tabB : tabA;
    const float* __restrict__ bias = chain ? bo : bc;
    const int el = lane >> 5;                    // edge sublane 0/1
    const int fl = lane & 31;                    // feature-pair index
    const int coloff = half * 64 + fl * 2;

    const int start = ofs[i], end = ofs[i + 1];
    float a0 = 0.f, a1 = 0.f;

    for (int base = start; base < end; base += 64) {
        int n = end - base; if (n > 64) n = 64;
        if (lane < n) s_pk[w][lane] = csr_pk[base + lane];
        // wave-synchronous: LDS ops from one wave are in-order; no barrier needed
        int j = el;
        for (; j + 6 < n; j += 8) {
            uint2 ea = s_pk[w][j],     eb = s_pk[w][j + 2];
            uint2 ec = s_pk[w][j + 4], ed = s_pk[w][j + 6];
            float ca = __uint_as_float(ea.y), cb = __uint_as_float(eb.y);
            float cc = __uint_as_float(ec.y), cd = __uint_as_float(ed.y);
            unsigned pa = *reinterpret_cast<const unsigned*>(&tab[(size_t)ea.x * 128 + coloff]);
            unsigned pb = *reinterpret_cast<const unsigned*>(&tab[(size_t)eb.x * 128 + coloff]);
            unsigned pc = *reinterpret_cast<const unsigned*>(&tab[(size_t)ec.x * 128 + coloff]);
            unsigned pd = *reinterpret_cast<const unsigned*>(&tab[(size_t)ed.x * 128 + coloff]);
            a0 = fmaf(bflo(pa), ca, a0); a1 = fmaf(bfhi(pa), ca, a1);
            a0 = fmaf(bflo(pb), cb, a0); a1 = fmaf(bfhi(pb), cb, a1);
            a0 = fmaf(bflo(pc), cc, a0); a1 = fmaf(bfhi(pc), cc, a1);
            a0 = fmaf(bflo(pd), cd, a0); a1 = fmaf(bfhi(pd), cd, a1);
        }
        for (; j < n; j += 2) {
            uint2 ee = s_pk[w][j];
            float cf = __uint_as_float(ee.y);
            unsigned pv = *reinterpret_cast<const unsigned*>(&tab[(size_t)ee.x * 128 + coloff]);
            a0 = fmaf(bflo(pv), cf, a0);
            a1 = fmaf(bfhi(pv), cf, a1);
        }
    }
    a0 += __shfl_xor(a0, 32);
    a1 += __shfl_xor(a1, 32);
    if (el == 0) {
        float di = deg_inv[i];
        float c = 2.f * di * di;
        unsigned pv = *reinterpret_cast<const unsigned*>(&tab[(size_t)i * 128 + coloff]);
        a0 = fmaf(bflo(pv), c, a0);
        a1 = fmaf(bfhi(pv), c, a1);
        a0 += bias[coloff];
        a1 += bias[coloff + 1];
        a0 = (a0 > 0.f) ? a0 : NEG_SLOPE * a0;
        a1 = (a1 > 0.f) ? a1 : NEG_SLOPE * a1;
        int col = (chain ? gcol : hcol) + coloff;
        unsigned o = (unsigned)f2bf(a0) | ((unsigned)f2bf(a1) << 16);
        *reinterpret_cast<unsigned*>(&outb[(size_t)i * 768 + col]) = o;
    }
}

// ---------------- final 2-wide heads: wave per node ----------------
__global__ __launch_bounds__(256) void heads_kernel(
    const float* __restrict__ tmpH,
    const float* __restrict__ Wod, const float* __restrict__ bod,
    const float* __restrict__ Wos, const float* __restrict__ bos,
    float* __restrict__ out)
{
    int w = threadIdx.x >> 6, lane = threadIdx.x & 63;
    int i = blockIdx.x * 4 + w;
    if (i >= NN) return;
    float a0 = 0.f, a1 = 0.f, d0 = 0.f, d1 = 0.f;
#pragma unroll
    for (int p = 0; p < 2; p++) {
        int k = lane + p * 64;
        float vd = tmpH[(size_t)i * 256 + k];
        float vs = tmpH[(size_t)i * 256 + 128 + k];
        a0 = fmaf(vd, Wod[k * 2 + 0], a0);
        a1 = fmaf(vd, Wod[k * 2 + 1], a1);
        d0 = fmaf(vs, Wos[k * 2 + 0], d0);
        d1 = fmaf(vs, Wos[k * 2 + 1], d1);
    }
    for (int off = 32; off; off >>= 1) {
        a0 += __shfl_down(a0, off);
        a1 += __shfl_down(a1, off);
        d0 += __shfl_down(d0, off);
        d1 += __shfl_down(d1, off);
    }
    if (lane == 0) {
        out[(size_t)i * 4 + 0] = a0 + bod[0];
        out[(size_t)i * 4 + 1] = a1 + bod[1];
        out[(size_t)i * 4 + 2] = d0 + bos[0];
        out[(size_t)i * 4 + 3] = d1 + bos[1];
    }
}

// ---------------- launch ----------------
extern "C" void kernel_launch(void* const* d_in, const int* in_sizes, int n_in,
                              void* d_out, int out_size, void* d_ws, size_t ws_size,
                              hipStream_t stream)
{
    const float* x      = (const float*)d_in[0];
    const float* x_ft   = (const float*)d_in[1];
    const int*   eidx   = (const int*)d_in[2];
    const float* W_pe   = (const float*)d_in[3];
    const float* b_pe   = (const float*)d_in[4];
    const float* W_gos  = (const float*)d_in[5];
    const float* b_gos  = (const float*)d_in[6];
    const float* W_prot = (const float*)d_in[7];
    const float* b_prot = (const float*)d_in[8];
    const float* W_om0  = (const float*)d_in[9];
    const float* b_om0  = (const float*)d_in[10];
    const float* W_om1  = (const float*)d_in[11];
    const float* b_om1  = (const float*)d_in[12];
    const float* W_om2  = (const float*)d_in[13];
    const float* b_om2  = (const float*)d_in[14];
    const float* W_om3  = (const float*)d_in[15];
    const float* b_om3  = (const float*)d_in[16];
    const float* W_c[3] = {(const float*)d_in[17], (const float*)d_in[21], (const float*)d_in[25]};
    const float* b_c[3] = {(const float*)d_in[18], (const float*)d_in[22], (const float*)d_in[26]};
    const float* W_o[3] = {(const float*)d_in[19], (const float*)d_in[23], (const float*)d_in[27]};
    const float* b_o[3] = {(const float*)d_in[20], (const float*)d_in[24], (const float*)d_in[28]};
    const float* W_lat  = (const float*)d_in[29];
    const float* b_lat  = (const float*)d_in[30];
    const float* W_drug = (const float*)d_in[31];
    const float* b_drug = (const float*)d_in[32];
    const float* W_dis  = (const float*)d_in[33];
    const float* b_dis  = (const float*)d_in[34];
    const float* W_odrug= (const float*)d_in[35];
    const float* b_odrug= (const float*)d_in[36];
    const float* W_odis = (const float*)d_in[37];
    const float* b_odis = (const float*)d_in[38];
    float* out = (float*)d_out;

    const int* e_src = eidx;
    const int* e_dst = eidx + NE;

    char* p = (char*)d_ws;
    auto alloc = [&](size_t bytes) -> void* {
        void* r = (void*)p;
        p += (bytes + 255) & ~(size_t)255;
        return r;
    };
    ushort_t* Wt    = (ushort_t*)alloc((size_t)WT_TOTAL * 2);
    float* bcat     = (float*)alloc(384 * 4);
    float* bomc     = (float*)alloc(384 * 4);
    float* bheads   = (float*)alloc(256 * 4);
    float* deg_inv  = (float*)alloc((size_t)NN * 4);
    int*   cnt      = (int*)alloc((size_t)NN * 4);
    int*   ofs      = (int*)alloc((size_t)(NN + 1) * 4);
    int*   cursor   = (int*)alloc((size_t)NN * 4);
    int*   bsum     = (int*)alloc((size_t)NSCAN * 4);
    int*   boff     = (int*)alloc((size_t)NSCAN * 4);
    uint2* csr_pk   = (uint2*)alloc((size_t)NE * 8);
    ushort_t* xb    = (ushort_t*)alloc((size_t)NNP * 736 * 2);
    ushort_t* xftb  = (ushort_t*)alloc((size_t)NNP * 64 * 2);
    ushort_t* h0b   = (ushort_t*)alloc((size_t)NNP * 384 * 2);
    ushort_t* g0b   = (ushort_t*)alloc((size_t)NNP * 384 * 2);
    ushort_t* jkb   = (ushort_t*)alloc((size_t)NNP * 768 * 2);
    ushort_t* zb    = (ushort_t*)alloc((size_t)NNP * 384 * 2);
    ushort_t* tmpAb = (ushort_t*)alloc((size_t)NNP * 128 * 2);
    ushort_t* tmpBb = (ushort_t*)alloc((size_t)NNP * 128 * 2);
    float* tmpH     = (float*)alloc((size_t)NNP * 256 * 4);
    (void)ws_size; (void)in_sizes; (void)n_in; (void)out_size;

    // 1. pack + transpose weights to bf16 [M][K]
    {
        int total = WT_TOTAL + 384 + 384 + 256;
        pack_weights<<<dim3((total + 255) / 256), dim3(256), 0, stream>>>(
            W_pe, W_gos, W_prot, b_pe, b_gos, b_prot,
            W_om0, W_om1, W_om2, W_om3, b_om0, b_om1, b_om2, b_om3,
            W_c[0], W_o[0], W_c[1], W_o[1], W_c[2], W_o[2],
            W_lat, W_drug, W_dis, b_drug, b_dis, Wt, bcat, bomc, bheads);
    }
    // 2. convert inputs to bf16
    convert_x<<<dim3((NN * 736 / 4 + 255) / 256), dim3(256), 0, stream>>>(x, xb);
    convert_xft<<<dim3((NN * 64 + 255) / 256), dim3(256), 0, stream>>>(x_ft, xftb);

    // 3. degree + CSR (sliced atomics, hierarchical scan, packed fill)
    hipMemsetAsync(cnt, 0, (size_t)NN * 4, stream);
    count_deg_sliced<<<dim3(NSL * FBPS), dim3(256), 0, stream>>>(e_dst, cnt);
    make_deginv<<<dim3((NN + 255) / 256), dim3(256), 0, stream>>>(cnt, deg_inv);
    scan_blocksums<<<dim3(NSCAN), dim3(256), 0, stream>>>(cnt, bsum);
    scan_tops<<<dim3(1), dim3(128), 0, stream>>>(bsum, boff, ofs);
    scan_apply<<<dim3(NSCAN), dim3(256), 0, stream>>>(cnt, boff, ofs, cursor);
    fill_csr_sliced<<<dim3(NSL * FBPS), dim3(256), 0, stream>>>(e_src, e_dst, deg_inv, cursor, csr_pk);

    // 4. input MLPs (bf16 MFMA, bf16 out)
    mfma_gemm<128, true, true><<<dim3(3, 157), dim3(256), 0, stream>>>(
        xb, 736, Wt + O_CAT, bcat, nullptr, h0b, 384, NN, 736);
    mfma_gemm<128, true, true><<<dim3(3, 157), dim3(256), 0, stream>>>(
        xftb, 64, Wt + O_OM, bomc, nullptr, g0b, 384, NN, 64);

    // 5. three GCN layers. jkb = bf16 [h1 h2 h3 g1 g2 g3], stride 768
    mfma_gemm_dual<<<dim3(2, 157, 2), dim3(256), 0, stream>>>(
        h0b, g0b, 384, Wt + O_C0, Wt + O_O0, tmpAb, tmpBb, 128, NN, 384);
    aggregate_wave<<<dim3(NN), dim3(256), 0, stream>>>(
        tmpAb, tmpBb, b_c[0], b_o[0], ofs, csr_pk, deg_inv, jkb, 0, 384);

    mfma_gemm_dual<<<dim3(2, 157, 2), dim3(256), 0, stream>>>(
        jkb + 0, jkb + 384, 768, Wt + O_C1, Wt + O_O1, tmpAb, tmpBb, 128, NN, 128);
    aggregate_wave<<<dim3(NN), dim3(256), 0, stream>>>(
        tmpAb, tmpBb, b_c[1], b_o[1], ofs, csr_pk, deg_inv, jkb, 128, 512);

    mfma_gemm_dual<<<dim3(2, 157, 2), dim3(256), 0, stream>>>(
        jkb + 128, jkb + 512, 768, Wt + O_C2, Wt + O_O2, tmpAb, tmpBb, 128, NN, 128);
    aggregate_wave<<<dim3(NN), dim3(256), 0, stream>>>(
        tmpAb, tmpBb, b_c[2], b_o[2], ofs, csr_pk, deg_inv, jkb, 256, 640);

    // 6. latent: zb = act(jkb @ W_lat + b_lat), bf16
    mfma_gemm<128, true, true><<<dim3(3, 157), dim3(256), 0, stream>>>(
        jkb, 768, Wt + O_LAT, b_lat, nullptr, zb, 384, NN, 768);

    // 7. fused heads GEMM (M=256): tmpH = act(zb @ [Wd|Ws] + [bd|bs]), fp32
    mfma_gemm<128, true, false><<<dim3(2, 157), dim3(256), 0, stream>>>(
        zb, 384, Wt + O_HEADS, bheads, tmpH, nullptr, 256, NN, 384);
    heads_kernel<<<dim3((NN + 3) / 4), dim3(256), 0, stream>>>(
        tmpH, W_odrug, b_odrug, W_odis, b_odis, out);
}